// Round 1
// baseline (706.283 us; speedup 1.0000x reference)
//
#include <hip/hip_runtime.h>
#include <hip/hip_bf16.h>

// SageLayer2: out = normalize(tanh(softmax(Q·K^T)·V))
// Restructured: precompute K/V for the whole table (shared across gathers),
// Q only for the 20K query nodes, then a gather+attention kernel.
//
// Phase 1: KVtab[T][512] = feat @ [Wk;Wv]^T + [bk;bv]   (T=100000)
//          Q[N][256]     = feat[node_ids] @ Wq^T + bq   (N=20000)
// Phase 2: per node: scores = Q·Ktab[ids], softmax, mix = attn·Vtab[ids],
//          out = tanh(mix)/max(||tanh(mix)||,1e-12)

#define D 256
#define BM 128
#define BN 128
#define BK 32

// C[m][n] = sum_e A[row(m)][e] * B[n0+n][e] + bias[n0+n]
// A rows gathered through idx (or identity if idx==nullptr). K-dim fixed = 256.
__global__ __launch_bounds__(256) void gemm_nt_bias(
    const float* __restrict__ A, const int* __restrict__ idx, int M,
    const float* __restrict__ B, const float* __restrict__ bias,
    float* __restrict__ C, int ldc)
{
    __shared__ float As[BK][BM];   // transposed: As[k][m]
    __shared__ float Bs[BK][BN];   // transposed: Bs[k][n]
    __shared__ int rowids[BM];

    const int t  = threadIdx.x;
    const int m0 = blockIdx.x * BM;
    const int n0 = blockIdx.y * BN;
    const int tx = t & 15;         // 16 cols of threads -> 8 C-cols each
    const int ty = t >> 4;         // 16 rows of threads -> 8 C-rows each

    if (t < BM) {
        int mg = m0 + t;
        int r  = (mg < M) ? mg : (M - 1);      // clamp tail (stores guarded)
        rowids[t] = idx ? idx[r] : r;
    }
    __syncthreads();

    float acc[8][8];
    #pragma unroll
    for (int i = 0; i < 8; ++i)
        #pragma unroll
        for (int j = 0; j < 8; ++j) acc[i][j] = 0.f;

    for (int kb = 0; kb < D; kb += BK) {
        // stage A and B tiles (transposed) into LDS
        #pragma unroll
        for (int i = 0; i < 4; ++i) {
            int f  = t + i * 256;       // 0..1023 float4 slots
            int m  = f >> 3;            // 0..127
            int k4 = (f & 7) * 4;       // 0,4,...,28
            float4 av = *(const float4*)(A + (size_t)rowids[m] * D + kb + k4);
            As[k4 + 0][m] = av.x; As[k4 + 1][m] = av.y;
            As[k4 + 2][m] = av.z; As[k4 + 3][m] = av.w;
            float4 bv4 = *(const float4*)(B + (size_t)(n0 + m) * D + kb + k4);
            Bs[k4 + 0][m] = bv4.x; Bs[k4 + 1][m] = bv4.y;
            Bs[k4 + 2][m] = bv4.z; Bs[k4 + 3][m] = bv4.w;
        }
        __syncthreads();

        #pragma unroll
        for (int k = 0; k < BK; ++k) {
            float a[8], b[8];
            *(float4*)&a[0] = *(const float4*)&As[k][ty * 8];
            *(float4*)&a[4] = *(const float4*)&As[k][ty * 8 + 4];
            *(float4*)&b[0] = *(const float4*)&Bs[k][tx * 8];
            *(float4*)&b[4] = *(const float4*)&Bs[k][tx * 8 + 4];
            #pragma unroll
            for (int i = 0; i < 8; ++i)
                #pragma unroll
                for (int j = 0; j < 8; ++j)
                    acc[i][j] = fmaf(a[i], b[j], acc[i][j]);
        }
        __syncthreads();
    }

    float bb[8];
    #pragma unroll
    for (int j = 0; j < 8; ++j) bb[j] = bias[n0 + tx * 8 + j];

    #pragma unroll
    for (int i = 0; i < 8; ++i) {
        int mg = m0 + ty * 8 + i;
        if (mg < M) {
            float* cp = C + (size_t)mg * ldc + n0 + tx * 8;
            float4 v0, v1;
            v0.x = acc[i][0] + bb[0]; v0.y = acc[i][1] + bb[1];
            v0.z = acc[i][2] + bb[2]; v0.w = acc[i][3] + bb[3];
            v1.x = acc[i][4] + bb[4]; v1.y = acc[i][5] + bb[5];
            v1.z = acc[i][6] + bb[6]; v1.w = acc[i][7] + bb[7];
            *(float4*)cp       = v0;
            *(float4*)(cp + 4) = v1;
        }
    }
}

// One block (256 thr = 4 waves) per node. KV row: [K(256) | V(256)].
__global__ __launch_bounds__(256) void attn_kernel(
    const int* __restrict__ node_ids, const int* __restrict__ neigh_ids,
    const float* __restrict__ Q, const float* __restrict__ KV,
    float* __restrict__ out, int S /*=32*/)
{
    const int n = blockIdx.x;
    const int t = threadIdx.x;
    const int w = t >> 6;      // wave 0..3
    const int l = t & 63;      // lane

    __shared__ int   ids[64];
    __shared__ float sc[64];
    __shared__ float red[4];
    __shared__ float snorm;

    const int SP1 = S + 1;     // 33
    if (t == 0) ids[0] = node_ids[n];
    if (t < S)  ids[1 + t] = neigh_ids[n * S + t];
    __syncthreads();

    // ---- scores: each wave handles k = w, w+4, ... ----
    const float4* Q4 = (const float4*)Q + (size_t)n * 64;
    float4 q = Q4[l];
    const float4* KV4 = (const float4*)KV;
    for (int k = w; k < SP1; k += 4) {
        const float4* Krow = KV4 + (size_t)ids[k] * 128;   // first 64 f4 = K
        float4 kr = Krow[l];
        float p = q.x * kr.x + q.y * kr.y + q.z * kr.z + q.w * kr.w;
        #pragma unroll
        for (int off = 32; off > 0; off >>= 1) p += __shfl_down(p, off);
        if (l == 0) sc[k] = p;
    }
    __syncthreads();

    // ---- softmax over SP1 entries (wave 0) ----
    if (t < 64) {
        float v = (t < SP1) ? sc[t] : -1e30f;
        float m = v;
        #pragma unroll
        for (int off = 32; off > 0; off >>= 1) m = fmaxf(m, __shfl_down(m, off));
        m = __shfl(m, 0);
        float e = (t < SP1) ? __expf(v - m) : 0.f;
        float s = e;
        #pragma unroll
        for (int off = 32; off > 0; off >>= 1) s += __shfl_down(s, off);
        s = __shfl(s, 0);
        if (t < SP1) sc[t] = e / s;
    }
    __syncthreads();

    // ---- mix: thread t owns dim d=t ----
    float mix = 0.f;
    for (int k = 0; k < SP1; ++k) {
        const float* Vrow = KV + (size_t)ids[k] * 512 + 256;
        mix = fmaf(sc[k], Vrow[t], mix);
    }

    float o = tanhf(mix);

    // ---- L2 norm over the 256 dims ----
    float ss = o * o;
    #pragma unroll
    for (int off = 32; off > 0; off >>= 1) ss += __shfl_down(ss, off);
    if (l == 0) red[w] = ss;
    __syncthreads();
    if (t == 0) {
        float tot = red[0] + red[1] + red[2] + red[3];
        snorm = 1.0f / fmaxf(sqrtf(tot), 1e-12f);
    }
    __syncthreads();

    out[(size_t)n * D + t] = o * snorm;
}

extern "C" void kernel_launch(void* const* d_in, const int* in_sizes, int n_in,
                              void* d_out, int out_size, void* d_ws, size_t ws_size,
                              hipStream_t stream) {
    const int*   node_ids  = (const int*)  d_in[0];
    const int*   neigh_ids = (const int*)  d_in[1];
    const float* feat      = (const float*)d_in[2];
    const float* Wq        = (const float*)d_in[3];
    const float* bq        = (const float*)d_in[4];
    const float* Wk        = (const float*)d_in[5];
    const float* bk        = (const float*)d_in[6];
    const float* Wv        = (const float*)d_in[7];
    const float* bv        = (const float*)d_in[8];
    float*       out       = (float*)d_out;

    const int N = in_sizes[0];            // 20000 nodes
    const int S = in_sizes[1] / N;        // 32 neighbors
    const int T = in_sizes[2] / D;        // 100000 table rows

    // workspace layout (floats)
    float* kv   = (float*)d_ws;                       // [T][512]  K|V interleaved
    float* q    = kv + (size_t)T * 512;               // [N][256]
    float* wkv  = q + (size_t)N * D;                  // [512][256] = [Wk;Wv]
    float* bkv  = wkv + 512 * D;                      // [512]
    // total: T*512 + N*256 + 512*256 + 512 floats ~= 225.8 MB

    // build concatenated [Wk;Wv] and [bk;bv]
    hipMemcpyAsync(wkv,           Wk, (size_t)D * D * sizeof(float), hipMemcpyDeviceToDevice, stream);
    hipMemcpyAsync(wkv + D * D,   Wv, (size_t)D * D * sizeof(float), hipMemcpyDeviceToDevice, stream);
    hipMemcpyAsync(bkv,           bk, (size_t)D * sizeof(float),     hipMemcpyDeviceToDevice, stream);
    hipMemcpyAsync(bkv + D,       bv, (size_t)D * sizeof(float),     hipMemcpyDeviceToDevice, stream);

    // Phase 1a: KV table GEMM  (T x 512)
    {
        dim3 grid((T + BM - 1) / BM, 512 / BN);
        gemm_nt_bias<<<grid, 256, 0, stream>>>(feat, nullptr, T, wkv, bkv, kv, 512);
    }
    // Phase 1b: Q rows (gathered)  (N x 256)
    {
        dim3 grid((N + BM - 1) / BM, D / BN);
        gemm_nt_bias<<<grid, 256, 0, stream>>>(feat, node_ids, N, Wq, bq, q, D);
    }
    // Phase 2: attention + tanh + normalize
    attn_kernel<<<N, 256, 0, stream>>>(node_ids, neigh_ids, q, kv, out, S);
}

// Round 3
// 412.129 us; speedup vs baseline: 1.7137x; 1.7137x over previous
//
#include <hip/hip_runtime.h>
#include <hip/hip_bf16.h>

#define D 256

typedef __bf16 bf16x8 __attribute__((ext_vector_type(8)));
typedef float  f32x4  __attribute__((ext_vector_type(4)));

static __device__ __forceinline__ unsigned short f2bf_rne(float f) {
    unsigned u = __float_as_uint(f);
    u += 0x7fff + ((u >> 16) & 1);
    return (unsigned short)(u >> 16);
}
static __device__ __forceinline__ float bf2f(unsigned short h) {
    return __uint_as_float(((unsigned)h) << 16);
}

static __device__ __forceinline__ void cp16(const unsigned short* g, unsigned short* l) {
    __builtin_amdgcn_global_load_lds(
        (const __attribute__((address_space(1))) void*)g,
        (__attribute__((address_space(3))) void*)l, 16, 0, 0);
}

// wstar[k] = sum_n Wk[n][k] * bq[n]   (tiny GEMV, one block)
__global__ __launch_bounds__(256) void wstar_kernel(
    const float* __restrict__ Wk, const float* __restrict__ bq,
    float* __restrict__ wstar)
{
    int k = threadIdx.x;
    float s = 0.f;
    for (int n = 0; n < D; ++n) s = fmaf(Wk[n * D + k], bq[n], s);
    wstar[k] = s;
}

// feat -> hi/lo bf16 split; c[t] = feat[t] . wstar  (one wave per row)
__global__ __launch_bounds__(256) void convert_feat_c(
    const float* __restrict__ feat, const float* __restrict__ wstar,
    unsigned short* __restrict__ hi, unsigned short* __restrict__ lo,
    float* __restrict__ c, int T)
{
    const int w = threadIdx.x >> 6, l = threadIdx.x & 63;
    const int row = blockIdx.x * 4 + w;
    if (row >= T) return;
    float4 v = ((const float4*)(feat + (size_t)row * D))[l];
    float4 ws = ((const float4*)wstar)[l];
    ushort4 h, lo4;
    h.x = f2bf_rne(v.x); lo4.x = f2bf_rne(v.x - bf2f(h.x));
    h.y = f2bf_rne(v.y); lo4.y = f2bf_rne(v.y - bf2f(h.y));
    h.z = f2bf_rne(v.z); lo4.z = f2bf_rne(v.z - bf2f(h.z));
    h.w = f2bf_rne(v.w); lo4.w = f2bf_rne(v.w - bf2f(h.w));
    ((ushort4*)(hi + (size_t)row * D))[l] = h;
    ((ushort4*)(lo + (size_t)row * D))[l] = lo4;
    float p = v.x * ws.x + v.y * ws.y + v.z * ws.z + v.w * ws.w;
    #pragma unroll
    for (int off = 32; off > 0; off >>= 1) p += __shfl_down(p, off);
    if (l == 0) c[row] = p;
}

// Build WqT/WkT (transposed, split) and Wv (split) in bf16 hi/lo.
__global__ __launch_bounds__(256) void convert_w(
    const float* __restrict__ Wq, const float* __restrict__ Wk,
    const float* __restrict__ Wv,
    unsigned short* __restrict__ wqT_h, unsigned short* __restrict__ wqT_l,
    unsigned short* __restrict__ wkT_h, unsigned short* __restrict__ wkT_l,
    unsigned short* __restrict__ wv_h,  unsigned short* __restrict__ wv_l)
{
    int i = blockIdx.x * 256 + threadIdx.x;     // 0..65535
    int r = i >> 8, cc = i & 255;
    int ti = cc * D + r;                        // transposed index
    float q = Wq[i]; unsigned short qh = f2bf_rne(q);
    wqT_h[ti] = qh; wqT_l[ti] = f2bf_rne(q - bf2f(qh));
    float k = Wk[i]; unsigned short kh = f2bf_rne(k);
    wkT_h[ti] = kh; wkT_l[ti] = f2bf_rne(k - bf2f(kh));
    float v = Wv[i]; unsigned short vh = f2bf_rne(v);
    wv_h[i] = vh; wv_l[i] = f2bf_rne(v - bf2f(vh));
}

// generic f32 -> bf16 hi/lo splitter (for MT)
__global__ __launch_bounds__(256) void split_f32(
    const float* __restrict__ x, unsigned short* __restrict__ hi,
    unsigned short* __restrict__ lo, int n4)
{
    int i = blockIdx.x * 256 + threadIdx.x;
    if (i >= n4) return;
    float4 v = ((const float4*)x)[i];
    ushort4 h, l;
    h.x = f2bf_rne(v.x); l.x = f2bf_rne(v.x - bf2f(h.x));
    h.y = f2bf_rne(v.y); l.y = f2bf_rne(v.y - bf2f(h.y));
    h.z = f2bf_rne(v.z); l.z = f2bf_rne(v.z - bf2f(h.z));
    h.w = f2bf_rne(v.w); l.w = f2bf_rne(v.w - bf2f(h.w));
    ((ushort4*)hi)[i] = h;
    ((ushort4*)lo)[i] = l;
}

// C[m][n] = sum_k A[row(m)][k] * B[n][k] (+bias[n]).  128x128 tile, BK=32,
// 16x16x32 bf16 MFMA, global_load_lds staging.
// SPLIT: 3-product hi/lo compensation (~f32 accuracy). !SPLIT: hi-only.
template <bool BF16OUT, bool SPLIT>
__global__ __launch_bounds__(256) void mfma_gemm(
    const unsigned short* __restrict__ Ah, const unsigned short* __restrict__ Al,
    const int* __restrict__ idx, int M,
    const unsigned short* __restrict__ Bh, const unsigned short* __restrict__ Bl,
    const float* __restrict__ bias, void* __restrict__ Cout, int ldc)
{
    __shared__ unsigned short sAh[128 * 32], sBh[128 * 32];
    __shared__ unsigned short sAl[SPLIT ? 128 * 32 : 8], sBl[SPLIT ? 128 * 32 : 8];

    const int t = threadIdx.x;
    const int w = t >> 6, lane = t & 63;
    const int quad = lane >> 4, mcol = lane & 15;
    const int m0 = blockIdx.x * 128, n0 = blockIdx.y * 128;
    const int wr = (w >> 1) * 64, wc = (w & 1) * 64;

    const int srow = w * 32 + (lane >> 2);
    const int kchunk = (lane & 3) * 8;

    int ar0 = m0 + srow;      if (ar0 > M - 1) ar0 = M - 1;
    int ar1 = m0 + srow + 16; if (ar1 > M - 1) ar1 = M - 1;
    if (idx) { ar0 = idx[ar0]; ar1 = idx[ar1]; }
    const unsigned short* a0h = Ah + (size_t)ar0 * D + kchunk;
    const unsigned short* a1h = Ah + (size_t)ar1 * D + kchunk;
    const unsigned short* b0h = Bh + (size_t)(n0 + srow) * D + kchunk;
    const unsigned short* b1h = Bh + (size_t)(n0 + srow + 16) * D + kchunk;
    const unsigned short *a0l = nullptr, *a1l = nullptr, *b0l = nullptr, *b1l = nullptr;
    if (SPLIT) {
        a0l = Al + (size_t)ar0 * D + kchunk;
        a1l = Al + (size_t)ar1 * D + kchunk;
        b0l = Bl + (size_t)(n0 + srow) * D + kchunk;
        b1l = Bl + (size_t)(n0 + srow + 16) * D + kchunk;
    }

    f32x4 acc[4][4];
    #pragma unroll
    for (int i = 0; i < 4; ++i)
        #pragma unroll
        for (int j = 0; j < 4; ++j) acc[i][j] = (f32x4){0.f, 0.f, 0.f, 0.f};

    #pragma unroll
    for (int kb = 0; kb < D; kb += 32) {
        cp16(a0h + kb, &sAh[w * 1024]);
        cp16(a1h + kb, &sAh[w * 1024 + 512]);
        cp16(b0h + kb, &sBh[w * 1024]);
        cp16(b1h + kb, &sBh[w * 1024 + 512]);
        if (SPLIT) {
            cp16(a0l + kb, &sAl[w * 1024]);
            cp16(a1l + kb, &sAl[w * 1024 + 512]);
            cp16(b0l + kb, &sBl[w * 1024]);
            cp16(b1l + kb, &sBl[w * 1024 + 512]);
        }
        __syncthreads();

        bf16x8 fah[4], fbh[4];
        #pragma unroll
        for (int i = 0; i < 4; ++i) {
            fah[i] = *(const bf16x8*)&sAh[(wr + i * 16 + mcol) * 32 + quad * 8];
            fbh[i] = *(const bf16x8*)&sBh[(wc + i * 16 + mcol) * 32 + quad * 8];
        }
        if (SPLIT) {
            bf16x8 fal[4], fbl[4];
            #pragma unroll
            for (int i = 0; i < 4; ++i) {
                fal[i] = *(const bf16x8*)&sAl[(wr + i * 16 + mcol) * 32 + quad * 8];
                fbl[i] = *(const bf16x8*)&sBl[(wc + i * 16 + mcol) * 32 + quad * 8];
            }
            #pragma unroll
            for (int i = 0; i < 4; ++i)
                #pragma unroll
                for (int j = 0; j < 4; ++j) {
                    acc[i][j] = __builtin_amdgcn_mfma_f32_16x16x32_bf16(fah[i], fbh[j], acc[i][j], 0, 0, 0);
                    acc[i][j] = __builtin_amdgcn_mfma_f32_16x16x32_bf16(fah[i], fbl[j], acc[i][j], 0, 0, 0);
                    acc[i][j] = __builtin_amdgcn_mfma_f32_16x16x32_bf16(fal[i], fbh[j], acc[i][j], 0, 0, 0);
                }
        } else {
            #pragma unroll
            for (int i = 0; i < 4; ++i)
                #pragma unroll
                for (int j = 0; j < 4; ++j)
                    acc[i][j] = __builtin_amdgcn_mfma_f32_16x16x32_bf16(fah[i], fbh[j], acc[i][j], 0, 0, 0);
        }
        __syncthreads();
    }

    float bb[4];
    #pragma unroll
    for (int j = 0; j < 4; ++j) bb[j] = bias ? bias[n0 + wc + j * 16 + mcol] : 0.f;

    #pragma unroll
    for (int i = 0; i < 4; ++i) {
        #pragma unroll
        for (int r = 0; r < 4; ++r) {
            int m = m0 + wr + i * 16 + quad * 4 + r;
            if (m < M) {
                #pragma unroll
                for (int j = 0; j < 4; ++j) {
                    float v = acc[i][j][r] + bb[j];
                    size_t off = (size_t)m * ldc + n0 + wc + j * 16 + mcol;
                    if (BF16OUT) ((unsigned short*)Cout)[off] = f2bf_rne(v);
                    else         ((float*)Cout)[off] = v;
                }
            }
        }
    }
}

// One block (4 waves) per node.
// score[k] = G[n] . feat[ids[k]] + c[ids[k]]   (all f32 — no K storage error)
// mix with bf16 Vtab; tanh; L2-normalize.
__global__ __launch_bounds__(256) void attn_kernel(
    const int* __restrict__ node_ids, const int* __restrict__ neigh_ids,
    const float* __restrict__ G, const float* __restrict__ feat,
    const float* __restrict__ c, const unsigned short* __restrict__ Vtab,
    float* __restrict__ out, int S)
{
    const int n = blockIdx.x, t = threadIdx.x;
    const int w = t >> 6, l = t & 63;

    __shared__ int   ids[64];
    __shared__ float sc[64];
    __shared__ float red[4];
    __shared__ float snorm;

    const int SP1 = S + 1;
    if (t == 0) ids[0] = node_ids[n];
    if (t < S)  ids[1 + t] = neigh_ids[n * S + t];
    __syncthreads();

    float4 g = ((const float4*)(G + (size_t)n * D))[l];

    for (int k = w; k < SP1; k += 4) {
        int id = ids[k];
        float4 f = ((const float4*)(feat + (size_t)id * D))[l];
        float p = g.x * f.x + g.y * f.y + g.z * f.z + g.w * f.w;
        #pragma unroll
        for (int off = 32; off > 0; off >>= 1) p += __shfl_down(p, off);
        if (l == 0) sc[k] = p + c[id];
    }
    __syncthreads();

    if (t < 64) {
        float v = (t < SP1) ? sc[t] : -1e30f;
        float m = v;
        #pragma unroll
        for (int off = 32; off > 0; off >>= 1) m = fmaxf(m, __shfl_down(m, off));
        m = __shfl(m, 0);
        float e = (t < SP1) ? __expf(v - m) : 0.f;
        float s = e;
        #pragma unroll
        for (int off = 32; off > 0; off >>= 1) s += __shfl_down(s, off);
        s = __shfl(s, 0);
        if (t < SP1) sc[t] = e / s;
    }
    __syncthreads();

    float mix = 0.f;
    for (int k = 0; k < SP1; ++k)
        mix = fmaf(sc[k], bf2f(Vtab[(size_t)ids[k] * D + t]), mix);

    float o = tanhf(mix);

    float ss = o * o;
    #pragma unroll
    for (int off = 32; off > 0; off >>= 1) ss += __shfl_down(ss, off);
    if (l == 0) red[w] = ss;
    __syncthreads();
    if (t == 0) {
        float tot = red[0] + red[1] + red[2] + red[3];
        snorm = 1.0f / fmaxf(sqrtf(tot), 1e-12f);
    }
    __syncthreads();

    out[(size_t)n * D + t] = o * snorm;
}

extern "C" void kernel_launch(void* const* d_in, const int* in_sizes, int n_in,
                              void* d_out, int out_size, void* d_ws, size_t ws_size,
                              hipStream_t stream) {
    const int*   node_ids  = (const int*)  d_in[0];
    const int*   neigh_ids = (const int*)  d_in[1];
    const float* feat      = (const float*)d_in[2];
    const float* Wq        = (const float*)d_in[3];
    const float* bq        = (const float*)d_in[4];
    const float* Wk        = (const float*)d_in[5];
    // const float* bk     = (const float*)d_in[6];   // softmax-invariant, unused
    const float* Wv        = (const float*)d_in[7];
    const float* bv        = (const float*)d_in[8];
    float*       out       = (float*)d_out;

    const int N = in_sizes[0];            // 20000
    const int S = in_sizes[1] / N;        // 32
    const int T = in_sizes[2] / D;        // 100000

    // ---- workspace layout (~155 MB) ----
    unsigned short* feat_hi = (unsigned short*)d_ws;            // T*256
    unsigned short* feat_lo = feat_hi + (size_t)T * D;          // T*256
    unsigned short* vtab    = feat_lo + (size_t)T * D;          // T*256 bf16
    float*          G       = (float*)(vtab + (size_t)T * D);   // N*256 f32
    float*          c       = G + (size_t)N * D;                // T f32
    float*          MT      = c + T;                            // 256*256 f32
    float*          wstar   = MT + D * D;                       // 256
    unsigned short* wqT_h   = (unsigned short*)(wstar + D);     // 6 x 256*256
    unsigned short* wqT_l   = wqT_h + D * D;
    unsigned short* wkT_h   = wqT_l + D * D;
    unsigned short* wkT_l   = wkT_h + D * D;
    unsigned short* wv_h    = wkT_l + D * D;
    unsigned short* wv_l    = wv_h + D * D;
    unsigned short* MT_h    = wv_l + D * D;                     // 2 x 256*256
    unsigned short* MT_l    = MT_h + D * D;

    wstar_kernel<<<1, 256, 0, stream>>>(Wk, bq, wstar);
    convert_feat_c<<<(T + 3) / 4, 256, 0, stream>>>(feat, wstar, feat_hi, feat_lo, c, T);
    convert_w<<<D * D / 256, 256, 0, stream>>>(Wq, Wk, Wv, wqT_h, wqT_l,
                                               wkT_h, wkT_l, wv_h, wv_l);

    // MT[j][i] = sum_d Wk[d][j]*Wq[d][i]  (rows j of MT pair with G columns)
    {
        dim3 grid(2, 2);
        mfma_gemm<false, true><<<grid, 256, 0, stream>>>(
            wkT_h, wkT_l, nullptr, D, wqT_h, wqT_l, nullptr, MT, D);
    }
    split_f32<<<(D * D / 4 + 255) / 256, 256, 0, stream>>>(MT, MT_h, MT_l, D * D / 4);

    // G[n][j] = feat[node_ids[n]] . MT[j]   (accuracy-critical: SPLIT)
    {
        dim3 grid((N + 127) / 128, 2);
        mfma_gemm<false, true><<<grid, 256, 0, stream>>>(
            feat_hi, feat_lo, node_ids, N, MT_h, MT_l, nullptr, G, D);
    }
    // Vtab[t] = feat[t] @ Wv^T + bv  (error channel is linear: hi-only)
    {
        dim3 grid((T + 127) / 128, 2);
        mfma_gemm<true, false><<<grid, 256, 0, stream>>>(
            feat_hi, nullptr, nullptr, T, wv_h, nullptr, bv, vtab, D);
    }
    attn_kernel<<<N, 256, 0, stream>>>(node_ids, neigh_ids, G, feat, c, vtab, out, S);
}

// Round 4
// 356.181 us; speedup vs baseline: 1.9829x; 1.1571x over previous
//
#include <hip/hip_runtime.h>
#include <hip/hip_bf16.h>

#define D 256

typedef __bf16 bf16x8 __attribute__((ext_vector_type(8)));
typedef float  f32x4  __attribute__((ext_vector_type(4)));

static __device__ __forceinline__ unsigned short f2bf_rne(float f) {
    unsigned u = __float_as_uint(f);
    u += 0x7fff + ((u >> 16) & 1);
    return (unsigned short)(u >> 16);
}
static __device__ __forceinline__ float bf2f(unsigned short h) {
    return __uint_as_float(((unsigned)h) << 16);
}
static __device__ __forceinline__ unsigned short f2h(float f) {
    _Float16 h = (_Float16)f;
    unsigned short u; __builtin_memcpy(&u, &h, 2); return u;
}
static __device__ __forceinline__ float h2f(unsigned short u) {
    _Float16 h; __builtin_memcpy(&h, &u, 2); return (float)h;
}

static __device__ __forceinline__ void cp16(const unsigned short* g, unsigned short* l) {
    __builtin_amdgcn_global_load_lds(
        (const __attribute__((address_space(1))) void*)g,
        (__attribute__((address_space(3))) void*)l, 16, 0, 0);
}

// wstar[k] = sum_n Wk[n][k] * bq[n]
__global__ __launch_bounds__(256) void wstar_kernel(
    const float* __restrict__ Wk, const float* __restrict__ bq,
    float* __restrict__ wstar)
{
    int k = threadIdx.x;
    float s = 0.f;
    for (int n = 0; n < D; ++n) s = fmaf(Wk[n * D + k], bq[n], s);
    wstar[k] = s;
}

// feat -> fp16 table; c[t] = feat[t] . wstar   (one wave per row)
__global__ __launch_bounds__(256) void convert_feat_f16_c(
    const float* __restrict__ feat, const float* __restrict__ wstar,
    unsigned short* __restrict__ f16tab, float* __restrict__ c, int T)
{
    const int w = threadIdx.x >> 6, l = threadIdx.x & 63;
    const int row = blockIdx.x * 4 + w;
    if (row >= T) return;
    float4 v = ((const float4*)(feat + (size_t)row * D))[l];
    float4 ws = ((const float4*)wstar)[l];
    ushort4 h;
    h.x = f2h(v.x); h.y = f2h(v.y); h.z = f2h(v.z); h.w = f2h(v.w);
    ((ushort4*)(f16tab + (size_t)row * D))[l] = h;
    float p = v.x * ws.x + v.y * ws.y + v.z * ws.z + v.w * ws.w;
    #pragma unroll
    for (int off = 32; off > 0; off >>= 1) p += __shfl_down(p, off);
    if (l == 0) c[row] = p;
}

// compact gathered rows -> bf16 hi/lo split (one wave per output row)
__global__ __launch_bounds__(256) void gather_split(
    const float* __restrict__ feat, const int* __restrict__ idx,
    unsigned short* __restrict__ hi, unsigned short* __restrict__ lo, int M)
{
    const int w = threadIdx.x >> 6, l = threadIdx.x & 63;
    const int m = blockIdx.x * 4 + w;
    if (m >= M) return;
    const int row = idx[m];
    float4 v = ((const float4*)(feat + (size_t)row * D))[l];
    ushort4 h, lo4;
    h.x = f2bf_rne(v.x); lo4.x = f2bf_rne(v.x - bf2f(h.x));
    h.y = f2bf_rne(v.y); lo4.y = f2bf_rne(v.y - bf2f(h.y));
    h.z = f2bf_rne(v.z); lo4.z = f2bf_rne(v.z - bf2f(h.z));
    h.w = f2bf_rne(v.w); lo4.w = f2bf_rne(v.w - bf2f(h.w));
    ((ushort4*)(hi + (size_t)m * D))[l] = h;
    ((ushort4*)(lo + (size_t)m * D))[l] = lo4;
}

// WqT/WkT (transposed, split) and Wv (split) in bf16 hi/lo.
__global__ __launch_bounds__(256) void convert_w(
    const float* __restrict__ Wq, const float* __restrict__ Wk,
    const float* __restrict__ Wv,
    unsigned short* __restrict__ wqT_h, unsigned short* __restrict__ wqT_l,
    unsigned short* __restrict__ wkT_h, unsigned short* __restrict__ wkT_l,
    unsigned short* __restrict__ wv_h,  unsigned short* __restrict__ wv_l)
{
    int i = blockIdx.x * 256 + threadIdx.x;
    int r = i >> 8, cc = i & 255;
    int ti = cc * D + r;
    float q = Wq[i]; unsigned short qh = f2bf_rne(q);
    wqT_h[ti] = qh; wqT_l[ti] = f2bf_rne(q - bf2f(qh));
    float k = Wk[i]; unsigned short kh = f2bf_rne(k);
    wkT_h[ti] = kh; wkT_l[ti] = f2bf_rne(k - bf2f(kh));
    float v = Wv[i]; unsigned short vh = f2bf_rne(v);
    wv_h[i] = vh; wv_l[i] = f2bf_rne(v - bf2f(vh));
}

__global__ __launch_bounds__(256) void split_f32(
    const float* __restrict__ x, unsigned short* __restrict__ hi,
    unsigned short* __restrict__ lo, int n4)
{
    int i = blockIdx.x * 256 + threadIdx.x;
    if (i >= n4) return;
    float4 v = ((const float4*)x)[i];
    ushort4 h, l;
    h.x = f2bf_rne(v.x); l.x = f2bf_rne(v.x - bf2f(h.x));
    h.y = f2bf_rne(v.y); l.y = f2bf_rne(v.y - bf2f(h.y));
    h.z = f2bf_rne(v.z); l.z = f2bf_rne(v.z - bf2f(h.z));
    h.w = f2bf_rne(v.w); l.w = f2bf_rne(v.w - bf2f(h.w));
    ((ushort4*)hi)[i] = h;
    ((ushort4*)lo)[i] = l;
}

// C[m][n] = sum_k A[m][k]*B[n][k] (+bias[n]).  128x128 tile, BK=32,
// 16x16x32 bf16 MFMA.  SPLIT: 3-product hi/lo compensation (~f32).
template <bool BF16OUT, bool SPLIT>
__global__ __launch_bounds__(256) void mfma_gemm(
    const unsigned short* __restrict__ Ah, const unsigned short* __restrict__ Al,
    const int* __restrict__ idx, int M,
    const unsigned short* __restrict__ Bh, const unsigned short* __restrict__ Bl,
    const float* __restrict__ bias, void* __restrict__ Cout, int ldc)
{
    __shared__ unsigned short sAh[128 * 32], sBh[128 * 32];
    __shared__ unsigned short sAl[SPLIT ? 128 * 32 : 8], sBl[SPLIT ? 128 * 32 : 8];

    const int t = threadIdx.x;
    const int w = t >> 6, lane = t & 63;
    const int quad = lane >> 4, mcol = lane & 15;
    const int m0 = blockIdx.x * 128, n0 = blockIdx.y * 128;
    const int wr = (w >> 1) * 64, wc = (w & 1) * 64;

    const int srow = w * 32 + (lane >> 2);
    const int kchunk = (lane & 3) * 8;

    int ar0 = m0 + srow;      if (ar0 > M - 1) ar0 = M - 1;
    int ar1 = m0 + srow + 16; if (ar1 > M - 1) ar1 = M - 1;
    if (idx) { ar0 = idx[ar0]; ar1 = idx[ar1]; }
    const unsigned short* a0h = Ah + (size_t)ar0 * D + kchunk;
    const unsigned short* a1h = Ah + (size_t)ar1 * D + kchunk;
    const unsigned short* b0h = Bh + (size_t)(n0 + srow) * D + kchunk;
    const unsigned short* b1h = Bh + (size_t)(n0 + srow + 16) * D + kchunk;
    const unsigned short *a0l = nullptr, *a1l = nullptr, *b0l = nullptr, *b1l = nullptr;
    if (SPLIT) {
        a0l = Al + (size_t)ar0 * D + kchunk;
        a1l = Al + (size_t)ar1 * D + kchunk;
        b0l = Bl + (size_t)(n0 + srow) * D + kchunk;
        b1l = Bl + (size_t)(n0 + srow + 16) * D + kchunk;
    }

    f32x4 acc[4][4];
    #pragma unroll
    for (int i = 0; i < 4; ++i)
        #pragma unroll
        for (int j = 0; j < 4; ++j) acc[i][j] = (f32x4){0.f, 0.f, 0.f, 0.f};

    #pragma unroll
    for (int kb = 0; kb < D; kb += 32) {
        cp16(a0h + kb, &sAh[w * 1024]);
        cp16(a1h + kb, &sAh[w * 1024 + 512]);
        cp16(b0h + kb, &sBh[w * 1024]);
        cp16(b1h + kb, &sBh[w * 1024 + 512]);
        if (SPLIT) {
            cp16(a0l + kb, &sAl[w * 1024]);
            cp16(a1l + kb, &sAl[w * 1024 + 512]);
            cp16(b0l + kb, &sBl[w * 1024]);
            cp16(b1l + kb, &sBl[w * 1024 + 512]);
        }
        __syncthreads();

        bf16x8 fah[4], fbh[4];
        #pragma unroll
        for (int i = 0; i < 4; ++i) {
            fah[i] = *(const bf16x8*)&sAh[(wr + i * 16 + mcol) * 32 + quad * 8];
            fbh[i] = *(const bf16x8*)&sBh[(wc + i * 16 + mcol) * 32 + quad * 8];
        }
        if (SPLIT) {
            bf16x8 fal[4], fbl[4];
            #pragma unroll
            for (int i = 0; i < 4; ++i) {
                fal[i] = *(const bf16x8*)&sAl[(wr + i * 16 + mcol) * 32 + quad * 8];
                fbl[i] = *(const bf16x8*)&sBl[(wc + i * 16 + mcol) * 32 + quad * 8];
            }
            #pragma unroll
            for (int i = 0; i < 4; ++i)
                #pragma unroll
                for (int j = 0; j < 4; ++j) {
                    acc[i][j] = __builtin_amdgcn_mfma_f32_16x16x32_bf16(fah[i], fbh[j], acc[i][j], 0, 0, 0);
                    acc[i][j] = __builtin_amdgcn_mfma_f32_16x16x32_bf16(fah[i], fbl[j], acc[i][j], 0, 0, 0);
                    acc[i][j] = __builtin_amdgcn_mfma_f32_16x16x32_bf16(fal[i], fbh[j], acc[i][j], 0, 0, 0);
                }
        } else {
            #pragma unroll
            for (int i = 0; i < 4; ++i)
                #pragma unroll
                for (int j = 0; j < 4; ++j)
                    acc[i][j] = __builtin_amdgcn_mfma_f32_16x16x32_bf16(fah[i], fbh[j], acc[i][j], 0, 0, 0);
        }
        __syncthreads();
    }

    float bb[4];
    #pragma unroll
    for (int j = 0; j < 4; ++j) bb[j] = bias ? bias[n0 + wc + j * 16 + mcol] : 0.f;

    #pragma unroll
    for (int i = 0; i < 4; ++i) {
        #pragma unroll
        for (int r = 0; r < 4; ++r) {
            int m = m0 + wr + i * 16 + quad * 4 + r;
            if (m < M) {
                #pragma unroll
                for (int j = 0; j < 4; ++j) {
                    float v = acc[i][j][r] + bb[j];
                    size_t off = (size_t)m * ldc + n0 + wc + j * 16 + mcol;
                    if (BF16OUT) ((unsigned short*)Cout)[off] = f2bf_rne(v);
                    else         ((float*)Cout)[off] = v;
                }
            }
        }
    }
}

// One block per node. score[k] = G[n].f16row + c[id]; softmax;
// mixfeat = sum_k attn_k * f16row_k (rows stashed in LDS between phases);
// write mixfeat as bf16 hi/lo for the final Wv GEMM.
__global__ __launch_bounds__(256) void attn_kernel(
    const int* __restrict__ node_ids, const int* __restrict__ neigh_ids,
    const float* __restrict__ G, const unsigned short* __restrict__ f16tab,
    const float* __restrict__ c,
    unsigned short* __restrict__ mixf_h, unsigned short* __restrict__ mixf_l,
    int S)
{
    const int n = blockIdx.x, t = threadIdx.x;
    const int w = t >> 6, l = t & 63;

    __shared__ int   ids[64];
    __shared__ float sc[64];
    __shared__ unsigned short stash[33 * 256];   // fp16 rows

    const int SP1 = S + 1;
    if (t < SP1) ids[t] = (t == 0) ? node_ids[n] : neigh_ids[(size_t)n * S + t - 1];
    __syncthreads();

    float4 g = ((const float4*)(G + (size_t)n * D))[l];

    for (int k = w; k < SP1; k += 4) {
        int id = ids[k];
        ushort4 h4 = ((const ushort4*)(f16tab + (size_t)id * D))[l];
        ((ushort4*)(stash + k * D))[l] = h4;
        float p = g.x * h2f(h4.x) + g.y * h2f(h4.y) +
                  g.z * h2f(h4.z) + g.w * h2f(h4.w);
        #pragma unroll
        for (int off = 32; off > 0; off >>= 1) p += __shfl_down(p, off);
        if (l == 0) sc[k] = p + c[id];
    }
    __syncthreads();

    if (t < 64) {
        float v = (t < SP1) ? sc[t] : -1e30f;
        float m = v;
        #pragma unroll
        for (int off = 32; off > 0; off >>= 1) m = fmaxf(m, __shfl_down(m, off));
        m = __shfl(m, 0);
        float e = (t < SP1) ? __expf(v - m) : 0.f;
        float s = e;
        #pragma unroll
        for (int off = 32; off > 0; off >>= 1) s += __shfl_down(s, off);
        s = __shfl(s, 0);
        if (t < SP1) sc[t] = e / s;
    }
    __syncthreads();

    float mix = 0.f;
    for (int k = 0; k < SP1; ++k)
        mix = fmaf(sc[k], h2f(stash[k * D + t]), mix);

    unsigned short mh = f2bf_rne(mix);
    mixf_h[(size_t)n * D + t] = mh;
    mixf_l[(size_t)n * D + t] = f2bf_rne(mix - bf2f(mh));
}

// out = tanh(P) / max(||tanh(P)||, 1e-12)  (one wave per row)
__global__ __launch_bounds__(256) void tanh_norm(
    const float* __restrict__ P, float* __restrict__ out, int N)
{
    const int w = threadIdx.x >> 6, l = threadIdx.x & 63;
    const int row = blockIdx.x * 4 + w;
    if (row >= N) return;
    float4 v = ((const float4*)(P + (size_t)row * D))[l];
    float4 o;
    o.x = tanhf(v.x); o.y = tanhf(v.y); o.z = tanhf(v.z); o.w = tanhf(v.w);
    float ss = o.x * o.x + o.y * o.y + o.z * o.z + o.w * o.w;
    #pragma unroll
    for (int off = 32; off > 0; off >>= 1) ss += __shfl_down(ss, off);
    ss = __shfl(ss, 0);
    float inv = 1.0f / fmaxf(sqrtf(ss), 1e-12f);
    o.x *= inv; o.y *= inv; o.z *= inv; o.w *= inv;
    ((float4*)(out + (size_t)row * D))[l] = o;
}

extern "C" void kernel_launch(void* const* d_in, const int* in_sizes, int n_in,
                              void* d_out, int out_size, void* d_ws, size_t ws_size,
                              hipStream_t stream) {
    const int*   node_ids  = (const int*)  d_in[0];
    const int*   neigh_ids = (const int*)  d_in[1];
    const float* feat      = (const float*)d_in[2];
    const float* Wq        = (const float*)d_in[3];
    const float* bq        = (const float*)d_in[4];
    const float* Wk        = (const float*)d_in[5];
    // bk (d_in[6]) is softmax-invariant — unused
    const float* Wv        = (const float*)d_in[7];
    const float* bv        = (const float*)d_in[8];
    float*       out       = (float*)d_out;

    const int N = in_sizes[0];            // 20000
    const int S = in_sizes[1] / N;        // 32
    const int T = in_sizes[2] / D;        // 100000

    // ---- workspace (~135 MB) ----
    unsigned short* f16tab = (unsigned short*)d_ws;             // T*D fp16
    float*          c      = (float*)(f16tab + (size_t)T * D);  // T
    float*          G      = c + T;                             // N*D f32
    float*          P      = G + (size_t)N * D;                 // N*D f32
    unsigned short* gath_h = (unsigned short*)(P + (size_t)N * D); // N*D
    unsigned short* gath_l = gath_h + (size_t)N * D;            // N*D
    unsigned short* mixf_h = gath_l + (size_t)N * D;            // N*D
    unsigned short* mixf_l = mixf_h + (size_t)N * D;            // N*D
    unsigned short* wqT_h  = mixf_l + (size_t)N * D;            // 6 x D*D
    unsigned short* wqT_l  = wqT_h + D * D;
    unsigned short* wkT_h  = wqT_l + D * D;
    unsigned short* wkT_l  = wkT_h + D * D;
    unsigned short* wv_h   = wkT_l + D * D;
    unsigned short* wv_l   = wv_h + D * D;
    unsigned short* MT_h   = wv_l + D * D;                      // 2 x D*D
    unsigned short* MT_l   = MT_h + D * D;
    float*          MT     = (float*)(MT_l + D * D);            // D*D f32
    float*          wstar  = MT + D * D;                        // D

    wstar_kernel<<<1, 256, 0, stream>>>(Wk, bq, wstar);
    convert_feat_f16_c<<<(T + 3) / 4, 256, 0, stream>>>(feat, wstar, f16tab, c, T);
    convert_w<<<D * D / 256, 256, 0, stream>>>(Wq, Wk, Wv, wqT_h, wqT_l,
                                               wkT_h, wkT_l, wv_h, wv_l);
    gather_split<<<(N + 3) / 4, 256, 0, stream>>>(feat, node_ids, gath_h, gath_l, N);

    // MT[j][i] = (Wk^T Wq)[j][i]
    {
        dim3 grid(2, 2);
        mfma_gemm<false, true><<<grid, 256, 0, stream>>>(
            wkT_h, wkT_l, nullptr, D, wqT_h, wqT_l, nullptr, MT, D);
    }
    split_f32<<<(D * D / 4 + 255) / 256, 256, 0, stream>>>(MT, MT_h, MT_l, D * D / 4);

    // G[n][j] = feat[node_ids[n]] . MT[j]
    {
        dim3 grid((N + 127) / 128, 2);
        mfma_gemm<false, true><<<grid, 256, 0, stream>>>(
            gath_h, gath_l, nullptr, N, MT_h, MT_l, nullptr, G, D);
    }

    attn_kernel<<<N, 256, 0, stream>>>(node_ids, neigh_ids, G, f16tab, c,
                                       mixf_h, mixf_l, S);

    // P = mixfeat @ Wv^T + bv
    {
        dim3 grid((N + 127) / 128, 2);
        mfma_gemm<false, true><<<grid, 256, 0, stream>>>(
            mixf_h, mixf_l, nullptr, N, wv_h, wv_l, bv, P, D);
    }
    tanh_norm<<<(N + 3) / 4, 256, 0, stream>>>(P, out, N);
}

// Round 5
// 327.074 us; speedup vs baseline: 2.1594x; 1.0890x over previous
//
#include <hip/hip_runtime.h>
#include <hip/hip_bf16.h>

#define D 256

typedef __bf16 bf16x8 __attribute__((ext_vector_type(8)));
typedef float  f32x4  __attribute__((ext_vector_type(4)));
typedef unsigned short ushort8 __attribute__((ext_vector_type(8)));

static __device__ __forceinline__ unsigned short f2bf_rne(float f) {
    unsigned u = __float_as_uint(f);
    u += 0x7fff + ((u >> 16) & 1);
    return (unsigned short)(u >> 16);
}
static __device__ __forceinline__ float bf2f(unsigned short h) {
    return __uint_as_float(((unsigned)h) << 16);
}
static __device__ __forceinline__ unsigned short f2h(float f) {
    _Float16 h = (_Float16)f;
    unsigned short u; __builtin_memcpy(&u, &h, 2); return u;
}
static __device__ __forceinline__ float h2f(unsigned short u) {
    _Float16 h; __builtin_memcpy(&h, &u, 2); return (float)h;
}

static __device__ __forceinline__ void cp16(const unsigned short* g, unsigned short* l) {
    __builtin_amdgcn_global_load_lds(
        (const __attribute__((address_space(1))) void*)g,
        (__attribute__((address_space(3))) void*)l, 16, 0, 0);
}

// split 8 f32 -> bf16 hi + lo vectors
static __device__ __forceinline__ void split8(float4 a, float4 b,
                                              ushort8& h, ushort8& l) {
    float v[8] = {a.x, a.y, a.z, a.w, b.x, b.y, b.z, b.w};
    #pragma unroll
    for (int i = 0; i < 8; ++i) {
        unsigned short hh = f2bf_rne(v[i]);
        h[i] = hh;
        l[i] = f2bf_rne(v[i] - bf2f(hh));
    }
}

// blocks 0..255: WqT/WkT (transposed, split) + Wv (split).  block 256: wstar.
__global__ __launch_bounds__(256) void convert_w_wstar(
    const float* __restrict__ Wq, const float* __restrict__ Wk,
    const float* __restrict__ Wv, const float* __restrict__ bq,
    unsigned short* __restrict__ wqT_h, unsigned short* __restrict__ wqT_l,
    unsigned short* __restrict__ wkT_h, unsigned short* __restrict__ wkT_l,
    unsigned short* __restrict__ wv_h,  unsigned short* __restrict__ wv_l,
    float* __restrict__ wstar)
{
    if (blockIdx.x == 256) {
        // wstar[k] = sum_n Wk[n][k] * bq[n]
        int k = threadIdx.x;
        float s = 0.f;
        for (int n = 0; n < D; ++n) s = fmaf(Wk[n * D + k], bq[n], s);
        wstar[k] = s;
        return;
    }
    int i = blockIdx.x * 256 + threadIdx.x;
    int r = i >> 8, cc = i & 255;
    int ti = cc * D + r;
    float q = Wq[i]; unsigned short qh = f2bf_rne(q);
    wqT_h[ti] = qh; wqT_l[ti] = f2bf_rne(q - bf2f(qh));
    float k = Wk[i]; unsigned short kh = f2bf_rne(k);
    wkT_h[ti] = kh; wkT_l[ti] = f2bf_rne(k - bf2f(kh));
    float v = Wv[i]; unsigned short vh = f2bf_rne(v);
    wv_h[i] = vh; wv_l[i] = f2bf_rne(v - bf2f(vh));
}

// feat -> fp16 table; c[t] = feat[t] . wstar   (one wave per row)
__global__ __launch_bounds__(256) void convert_feat_f16_c(
    const float* __restrict__ feat, const float* __restrict__ wstar,
    unsigned short* __restrict__ f16tab, float* __restrict__ c, int T)
{
    const int w = threadIdx.x >> 6, l = threadIdx.x & 63;
    const int row = blockIdx.x * 4 + w;
    if (row >= T) return;
    float4 v = ((const float4*)(feat + (size_t)row * D))[l];
    float4 ws = ((const float4*)wstar)[l];
    ushort4 h;
    h.x = f2h(v.x); h.y = f2h(v.y); h.z = f2h(v.z); h.w = f2h(v.w);
    ((ushort4*)(f16tab + (size_t)row * D))[l] = h;
    float p = v.x * ws.x + v.y * ws.y + v.z * ws.z + v.w * ws.w;
    #pragma unroll
    for (int off = 32; off > 0; off >>= 1) p += __shfl_down(p, off);
    if (l == 0) c[row] = p;
}

// C[m][n] = sum_k A[row(m)][k]*B[n][k] (+bias[n]).  128x128 tile, BK=32,
// 16x16x32 bf16 MFMA, 3-product hi/lo compensation (~f32 accuracy).
// AF32: A is f32, gathered via idx, split to hi/lo during LDS staging.
// BF16PAIR_OUT: write C as bf16 hi/lo pair instead of f32.
template <bool BF16PAIR_OUT, bool AF32>
__global__ __launch_bounds__(256) void mfma_gemm(
    const unsigned short* __restrict__ Ah, const unsigned short* __restrict__ Al,
    const float* __restrict__ Af,
    const int* __restrict__ idx, int M,
    const unsigned short* __restrict__ Bh, const unsigned short* __restrict__ Bl,
    const float* __restrict__ bias,
    float* __restrict__ Cf, unsigned short* __restrict__ Ch,
    unsigned short* __restrict__ Cl, int ldc)
{
    __shared__ __align__(16) unsigned short sAh[128 * 32], sBh[128 * 32];
    __shared__ __align__(16) unsigned short sAl[128 * 32], sBl[128 * 32];

    const int t = threadIdx.x;
    const int w = t >> 6, lane = t & 63;
    const int quad = lane >> 4, mcol = lane & 15;
    const int m0 = blockIdx.x * 128, n0 = blockIdx.y * 128;
    const int wr = (w >> 1) * 64, wc = (w & 1) * 64;

    const int srow = w * 32 + (lane >> 2);
    const int kchunk = (lane & 3) * 8;

    int ar0 = m0 + srow;      if (ar0 > M - 1) ar0 = M - 1;
    int ar1 = m0 + srow + 16; if (ar1 > M - 1) ar1 = M - 1;
    if (idx) { ar0 = idx[ar0]; ar1 = idx[ar1]; }

    const unsigned short *a0h = nullptr, *a1h = nullptr, *a0l = nullptr, *a1l = nullptr;
    const float *af0 = nullptr, *af1 = nullptr;
    if constexpr (AF32) {
        af0 = Af + (size_t)ar0 * D + kchunk;
        af1 = Af + (size_t)ar1 * D + kchunk;
    } else {
        a0h = Ah + (size_t)ar0 * D + kchunk;
        a1h = Ah + (size_t)ar1 * D + kchunk;
        a0l = Al + (size_t)ar0 * D + kchunk;
        a1l = Al + (size_t)ar1 * D + kchunk;
    }
    const unsigned short* b0h = Bh + (size_t)(n0 + srow) * D + kchunk;
    const unsigned short* b1h = Bh + (size_t)(n0 + srow + 16) * D + kchunk;
    const unsigned short* b0l = Bl + (size_t)(n0 + srow) * D + kchunk;
    const unsigned short* b1l = Bl + (size_t)(n0 + srow + 16) * D + kchunk;

    f32x4 acc[4][4];
    #pragma unroll
    for (int i = 0; i < 4; ++i)
        #pragma unroll
        for (int j = 0; j < 4; ++j) acc[i][j] = (f32x4){0.f, 0.f, 0.f, 0.f};

    #pragma unroll
    for (int kb = 0; kb < D; kb += 32) {
        cp16(b0h + kb, &sBh[w * 1024]);
        cp16(b1h + kb, &sBh[w * 1024 + 512]);
        cp16(b0l + kb, &sBl[w * 1024]);
        cp16(b1l + kb, &sBl[w * 1024 + 512]);
        if constexpr (AF32) {
            float4 x0 = *(const float4*)(af0 + kb);
            float4 x1 = *(const float4*)(af0 + kb + 4);
            float4 y0 = *(const float4*)(af1 + kb);
            float4 y1 = *(const float4*)(af1 + kb + 4);
            ushort8 h, l;
            split8(x0, x1, h, l);
            *(ushort8*)&sAh[w * 1024 + lane * 8] = h;
            *(ushort8*)&sAl[w * 1024 + lane * 8] = l;
            split8(y0, y1, h, l);
            *(ushort8*)&sAh[w * 1024 + 512 + lane * 8] = h;
            *(ushort8*)&sAl[w * 1024 + 512 + lane * 8] = l;
        } else {
            cp16(a0h + kb, &sAh[w * 1024]);
            cp16(a1h + kb, &sAh[w * 1024 + 512]);
            cp16(a0l + kb, &sAl[w * 1024]);
            cp16(a1l + kb, &sAl[w * 1024 + 512]);
        }
        __syncthreads();

        bf16x8 fah[4], fbh[4], fal[4], fbl[4];
        #pragma unroll
        for (int i = 0; i < 4; ++i) {
            fah[i] = *(const bf16x8*)&sAh[(wr + i * 16 + mcol) * 32 + quad * 8];
            fbh[i] = *(const bf16x8*)&sBh[(wc + i * 16 + mcol) * 32 + quad * 8];
            fal[i] = *(const bf16x8*)&sAl[(wr + i * 16 + mcol) * 32 + quad * 8];
            fbl[i] = *(const bf16x8*)&sBl[(wc + i * 16 + mcol) * 32 + quad * 8];
        }
        #pragma unroll
        for (int i = 0; i < 4; ++i)
            #pragma unroll
            for (int j = 0; j < 4; ++j) {
                acc[i][j] = __builtin_amdgcn_mfma_f32_16x16x32_bf16(fah[i], fbh[j], acc[i][j], 0, 0, 0);
                acc[i][j] = __builtin_amdgcn_mfma_f32_16x16x32_bf16(fah[i], fbl[j], acc[i][j], 0, 0, 0);
                acc[i][j] = __builtin_amdgcn_mfma_f32_16x16x32_bf16(fal[i], fbh[j], acc[i][j], 0, 0, 0);
            }
        __syncthreads();
    }

    float bb[4];
    #pragma unroll
    for (int j = 0; j < 4; ++j) bb[j] = bias ? bias[n0 + wc + j * 16 + mcol] : 0.f;

    #pragma unroll
    for (int i = 0; i < 4; ++i) {
        #pragma unroll
        for (int r = 0; r < 4; ++r) {
            int m = m0 + wr + i * 16 + quad * 4 + r;
            if (m < M) {
                #pragma unroll
                for (int j = 0; j < 4; ++j) {
                    float v = acc[i][j][r] + bb[j];
                    size_t off = (size_t)m * ldc + n0 + wc + j * 16 + mcol;
                    if constexpr (BF16PAIR_OUT) {
                        unsigned short hh = f2bf_rne(v);
                        Ch[off] = hh;
                        Cl[off] = f2bf_rne(v - bf2f(hh));
                    } else {
                        Cf[off] = v;
                    }
                }
            }
        }
    }
}

// One WAVE per node, zero barriers, fully unrolled (S compile-time).
// Rows kept in registers; scores via butterfly shuffle; in-wave softmax;
// mix from registers with readlane broadcasts. Writes mixfeat f32.
template <int S>
__global__ __launch_bounds__(256) void attn_wave(
    const int* __restrict__ node_ids, const int* __restrict__ neigh_ids,
    const float* __restrict__ G, const unsigned short* __restrict__ f16tab,
    const float* __restrict__ c, float* __restrict__ mixf, int N)
{
    constexpr int SP1 = S + 1;
    const int w = threadIdx.x >> 6, l = threadIdx.x & 63;
    const int n = blockIdx.x * 4 + w;
    if (n >= N) return;

    int myid = 0;
    if (l < SP1) myid = (l == 0) ? node_ids[n] : neigh_ids[(size_t)n * S + (l - 1)];
    float myc = (l < SP1) ? c[myid] : 0.f;

    float4 g = ((const float4*)(G + (size_t)n * D))[l];

    ushort4 rows[SP1];
    #pragma unroll
    for (int k = 0; k < SP1; ++k) {
        int idk = __shfl(myid, k);
        rows[k] = ((const ushort4*)(f16tab + (size_t)idk * D))[l];
    }

    float score = -1e30f;
    #pragma unroll
    for (int k = 0; k < SP1; ++k) {
        ushort4 r = rows[k];
        float p = g.x * h2f(r.x) + g.y * h2f(r.y) +
                  g.z * h2f(r.z) + g.w * h2f(r.w);
        #pragma unroll
        for (int off = 1; off < 64; off <<= 1) p += __shfl_xor(p, off);
        if (l == k) score = p + myc;
    }

    float m = score;
    #pragma unroll
    for (int off = 1; off < 64; off <<= 1) m = fmaxf(m, __shfl_xor(m, off));
    float e = (l < SP1) ? __expf(score - m) : 0.f;
    float s = e;
    #pragma unroll
    for (int off = 1; off < 64; off <<= 1) s += __shfl_xor(s, off);
    float attn = e / s;

    float4 mix = {0.f, 0.f, 0.f, 0.f};
    #pragma unroll
    for (int k = 0; k < SP1; ++k) {
        float a = __shfl(attn, k);
        ushort4 r = rows[k];
        mix.x = fmaf(a, h2f(r.x), mix.x);
        mix.y = fmaf(a, h2f(r.y), mix.y);
        mix.z = fmaf(a, h2f(r.z), mix.z);
        mix.w = fmaf(a, h2f(r.w), mix.w);
    }
    ((float4*)(mixf + (size_t)n * D))[l] = mix;
}

// generic fallback (S != 32): block per node, dynamic loops
__global__ __launch_bounds__(256) void attn_dyn(
    const int* __restrict__ node_ids, const int* __restrict__ neigh_ids,
    const float* __restrict__ G, const unsigned short* __restrict__ f16tab,
    const float* __restrict__ c, float* __restrict__ mixf, int S)
{
    const int n = blockIdx.x, t = threadIdx.x;
    const int w = t >> 6, l = t & 63;
    __shared__ int   ids[128];
    __shared__ float sc[128];
    const int SP1 = S + 1;
    for (int k = t; k < SP1; k += 256)
        ids[k] = (k == 0) ? node_ids[n] : neigh_ids[(size_t)n * S + k - 1];
    __syncthreads();
    float4 g = ((const float4*)(G + (size_t)n * D))[l];
    for (int k = w; k < SP1; k += 4) {
        int id = ids[k];
        ushort4 h4 = ((const ushort4*)(f16tab + (size_t)id * D))[l];
        float p = g.x * h2f(h4.x) + g.y * h2f(h4.y) +
                  g.z * h2f(h4.z) + g.w * h2f(h4.w);
        #pragma unroll
        for (int off = 32; off > 0; off >>= 1) p += __shfl_down(p, off);
        if (l == 0) sc[k] = p + c[id];
    }
    __syncthreads();
    if (t < 64) {
        float v = (t < SP1) ? sc[t] : -1e30f;
        float m = v;
        #pragma unroll
        for (int off = 32; off > 0; off >>= 1) m = fmaxf(m, __shfl_down(m, off));
        m = __shfl(m, 0);
        float e = (t < SP1) ? __expf(v - m) : 0.f;
        float s = e;
        #pragma unroll
        for (int off = 32; off > 0; off >>= 1) s += __shfl_down(s, off);
        s = __shfl(s, 0);
        if (t < SP1) sc[t] = e / s;
    }
    __syncthreads();
    float mix = 0.f;
    for (int k = 0; k < SP1; ++k)
        mix = fmaf(sc[k], h2f(f16tab[(size_t)ids[k] * D + t]), mix);
    mixf[(size_t)n * D + t] = mix;
}

// out = tanh(P) / max(||tanh(P)||, 1e-12)  (one wave per row)
__global__ __launch_bounds__(256) void tanh_norm(
    const float* __restrict__ P, float* __restrict__ out, int N)
{
    const int w = threadIdx.x >> 6, l = threadIdx.x & 63;
    const int row = blockIdx.x * 4 + w;
    if (row >= N) return;
    float4 v = ((const float4*)(P + (size_t)row * D))[l];
    float4 o;
    o.x = tanhf(v.x); o.y = tanhf(v.y); o.z = tanhf(v.z); o.w = tanhf(v.w);
    float ss = o.x * o.x + o.y * o.y + o.z * o.z + o.w * o.w;
    #pragma unroll
    for (int off = 32; off > 0; off >>= 1) ss += __shfl_down(ss, off);
    ss = __shfl(ss, 0);
    float inv = 1.0f / fmaxf(sqrtf(ss), 1e-12f);
    o.x *= inv; o.y *= inv; o.z *= inv; o.w *= inv;
    ((float4*)(out + (size_t)row * D))[l] = o;
}

extern "C" void kernel_launch(void* const* d_in, const int* in_sizes, int n_in,
                              void* d_out, int out_size, void* d_ws, size_t ws_size,
                              hipStream_t stream) {
    const int*   node_ids  = (const int*)  d_in[0];
    const int*   neigh_ids = (const int*)  d_in[1];
    const float* feat      = (const float*)d_in[2];
    const float* Wq        = (const float*)d_in[3];
    const float* bq        = (const float*)d_in[4];
    const float* Wk        = (const float*)d_in[5];
    // bk (d_in[6]) is softmax-invariant — unused
    const float* Wv        = (const float*)d_in[7];
    const float* bv        = (const float*)d_in[8];
    float*       out       = (float*)d_out;

    const int N = in_sizes[0];            // 20000
    const int S = in_sizes[1] / N;        // 32
    const int T = in_sizes[2] / D;        // 100000

    // ---- workspace (~114 MB) ----
    unsigned short* f16tab = (unsigned short*)d_ws;             // T*D fp16
    float*          c      = (float*)(f16tab + (size_t)T * D);  // T
    float*          G      = c + T;                             // N*D f32
    float*          mixf   = G + (size_t)N * D;                 // N*D f32
    float*          P      = mixf + (size_t)N * D;              // N*D f32
    unsigned short* wqT_h  = (unsigned short*)(P + (size_t)N * D); // 6 x D*D
    unsigned short* wqT_l  = wqT_h + D * D;
    unsigned short* wkT_h  = wqT_l + D * D;
    unsigned short* wkT_l  = wkT_h + D * D;
    unsigned short* wv_h   = wkT_l + D * D;
    unsigned short* wv_l   = wv_h + D * D;
    unsigned short* MT_h   = wv_l + D * D;                      // 2 x D*D
    unsigned short* MT_l   = MT_h + D * D;
    float*          wstar  = (float*)(MT_l + D * D);            // D

    // 1) weight conversion + wstar (fused)
    convert_w_wstar<<<257, 256, 0, stream>>>(Wq, Wk, Wv, bq,
        wqT_h, wqT_l, wkT_h, wkT_l, wv_h, wv_l, wstar);

    // 2) fp16 feature table + c[t]
    convert_feat_f16_c<<<(T + 3) / 4, 256, 0, stream>>>(feat, wstar, f16tab, c, T);

    // 3) MT = Wk^T Wq, written directly as bf16 hi/lo
    {
        dim3 grid(2, 2);
        mfma_gemm<true, false><<<grid, 256, 0, stream>>>(
            wkT_h, wkT_l, nullptr, nullptr, D, wqT_h, wqT_l, nullptr,
            nullptr, MT_h, MT_l, D);
    }
    // 4) G[n] = feat[node_ids[n]] . MT  (f32 A, gathered, on-the-fly split)
    {
        dim3 grid((N + 127) / 128, 2);
        mfma_gemm<false, true><<<grid, 256, 0, stream>>>(
            nullptr, nullptr, feat, node_ids, N, MT_h, MT_l, nullptr,
            G, nullptr, nullptr, D);
    }
    // 5) attention -> mixfeat (f32)
    if (S == 32)
        attn_wave<32><<<(N + 3) / 4, 256, 0, stream>>>(
            node_ids, neigh_ids, G, f16tab, c, mixf, N);
    else
        attn_dyn<<<N, 256, 0, stream>>>(node_ids, neigh_ids, G, f16tab, c, mixf, S);

    // 6) P = mixfeat @ Wv^T + bv  (f32 A, on-the-fly split)
    {
        dim3 grid((N + 127) / 128, 2);
        mfma_gemm<false, true><<<grid, 256, 0, stream>>>(
            nullptr, nullptr, mixf, nullptr, N, wv_h, wv_l, bv,
            P, nullptr, nullptr, D);
    }
    // 7) tanh + L2 normalize
    tanh_norm<<<(N + 3) / 4, 256, 0, stream>>>(P, out, N);
}

// Round 6
// 286.734 us; speedup vs baseline: 2.4632x; 1.1407x over previous
//
#include <hip/hip_runtime.h>
#include <hip/hip_bf16.h>

#define D 256

typedef __bf16 bf16x8 __attribute__((ext_vector_type(8)));
typedef float  f32x4  __attribute__((ext_vector_type(4)));
typedef unsigned short ushort8v __attribute__((ext_vector_type(8)));

static __device__ __forceinline__ unsigned short f2bf_rne(float f) {
    unsigned u = __float_as_uint(f);
    u += 0x7fff + ((u >> 16) & 1);
    return (unsigned short)(u >> 16);
}
static __device__ __forceinline__ float bf2f(unsigned short h) {
    return __uint_as_float(((unsigned)h) << 16);
}
static __device__ __forceinline__ unsigned short f2h(float f) {
    _Float16 h = (_Float16)f;
    unsigned short u; __builtin_memcpy(&u, &h, 2); return u;
}
static __device__ __forceinline__ float h2f(unsigned short u) {
    _Float16 h; __builtin_memcpy(&h, &u, 2); return (float)h;
}

static __device__ __forceinline__ void cp16(const unsigned short* g, unsigned short* l) {
    __builtin_amdgcn_global_load_lds(
        (const __attribute__((address_space(1))) void*)g,
        (__attribute__((address_space(3))) void*)l, 16, 0, 0);
}

static __device__ __forceinline__ void split8(float4 a, float4 b,
                                              ushort8v& h, ushort8v& l) {
    float v[8] = {a.x, a.y, a.z, a.w, b.x, b.y, b.z, b.w};
    #pragma unroll
    for (int i = 0; i < 8; ++i) {
        unsigned short hh = f2bf_rne(v[i]);
        h[i] = hh;
        l[i] = f2bf_rne(v[i] - bf2f(hh));
    }
}

// ONE launch: [0, nbf) feat->fp16 blocks; [nbf, nbf+256) weight-split blocks;
// block nbf+256 computes wstar = Wk^T bq.
__global__ __launch_bounds__(256) void convert_all(
    const float* __restrict__ feat, int T, int nbf,
    const float* __restrict__ Wq, const float* __restrict__ Wk,
    const float* __restrict__ Wv, const float* __restrict__ bq,
    unsigned short* __restrict__ f16tab,
    unsigned short* __restrict__ wqT_h, unsigned short* __restrict__ wqT_l,
    unsigned short* __restrict__ wkT_h, unsigned short* __restrict__ wkT_l,
    unsigned short* __restrict__ wv_h,  unsigned short* __restrict__ wv_l,
    float* __restrict__ wstar)
{
    const int bx = blockIdx.x;
    if (bx < nbf) {
        const int w = threadIdx.x >> 6, l = threadIdx.x & 63;
        const int row = bx * 4 + w;
        if (row >= T) return;
        float4 v = ((const float4*)(feat + (size_t)row * D))[l];
        ushort4 h;
        h.x = f2h(v.x); h.y = f2h(v.y); h.z = f2h(v.z); h.w = f2h(v.w);
        ((ushort4*)(f16tab + (size_t)row * D))[l] = h;
        return;
    }
    const int wb = bx - nbf;
    if (wb == 256) {
        int k = threadIdx.x;
        float s = 0.f;
        for (int n = 0; n < D; ++n) s = fmaf(Wk[n * D + k], bq[n], s);
        wstar[k] = s;
        return;
    }
    int i = wb * 256 + threadIdx.x;
    int r = i >> 8, cc = i & 255;
    int ti = cc * D + r;
    float q = Wq[i]; unsigned short qh = f2bf_rne(q);
    wqT_h[ti] = qh; wqT_l[ti] = f2bf_rne(q - bf2f(qh));
    float k = Wk[i]; unsigned short kh = f2bf_rne(k);
    wkT_h[ti] = kh; wkT_l[ti] = f2bf_rne(k - bf2f(kh));
    float v = Wv[i]; unsigned short vh = f2bf_rne(v);
    wv_h[i] = vh; wv_l[i] = f2bf_rne(v - bf2f(vh));
}

// C[m][n] = sum_k A[row(m)][k]*B[n][k] (+bias[n]).  64x128 tile, BK=32,
// 16x16x32 bf16 MFMA, 3-product hi/lo split (~f32 accuracy).
// AF32: A is f32 (optionally gathered via idx), split on the fly.
template <bool BF16PAIR_OUT, bool AF32>
__global__ __launch_bounds__(256) void mfma_gemm64(
    const unsigned short* __restrict__ Ah, const unsigned short* __restrict__ Al,
    const float* __restrict__ Af,
    const int* __restrict__ idx, int M,
    const unsigned short* __restrict__ Bh, const unsigned short* __restrict__ Bl,
    const float* __restrict__ bias,
    float* __restrict__ Cf, unsigned short* __restrict__ Ch,
    unsigned short* __restrict__ Cl, int ldc)
{
    __shared__ __align__(16) unsigned short sAh[64 * 32], sAl[64 * 32];
    __shared__ __align__(16) unsigned short sBh[128 * 32], sBl[128 * 32];

    const int t = threadIdx.x;
    const int w = t >> 6, lane = t & 63;
    const int quad = lane >> 4, mcol = lane & 15;
    const int m0 = blockIdx.x * 64, n0 = blockIdx.y * 128;
    const int wc = w * 32;

    const int arow = t >> 2;              // 0..63
    const int kchunk = (t & 3) * 8;

    int ar = m0 + arow; if (ar > M - 1) ar = M - 1;
    if (idx) ar = idx[ar];

    const unsigned short *aph = nullptr, *apl = nullptr;
    const float *apf = nullptr;
    if constexpr (AF32) {
        apf = Af + (size_t)ar * D + kchunk;
    } else {
        aph = Ah + (size_t)ar * D + kchunk;
        apl = Al + (size_t)ar * D + kchunk;
    }
    const unsigned short* b0h = Bh + (size_t)(n0 + arow) * D + kchunk;
    const unsigned short* b1h = Bh + (size_t)(n0 + arow + 64) * D + kchunk;
    const unsigned short* b0l = Bl + (size_t)(n0 + arow) * D + kchunk;
    const unsigned short* b1l = Bl + (size_t)(n0 + arow + 64) * D + kchunk;

    f32x4 acc[4][2];
    #pragma unroll
    for (int i = 0; i < 4; ++i)
        #pragma unroll
        for (int j = 0; j < 2; ++j) acc[i][j] = (f32x4){0.f, 0.f, 0.f, 0.f};

    #pragma unroll
    for (int kb = 0; kb < D; kb += 32) {
        // B staging: wave-uniform base + lane*16  (rows w*16.., and +64)
        cp16(b0h + kb, &sBh[w * 512]);
        cp16(b1h + kb, &sBh[w * 512 + 2048]);
        cp16(b0l + kb, &sBl[w * 512]);
        cp16(b1l + kb, &sBl[w * 512 + 2048]);
        if constexpr (AF32) {
            float4 x0 = *(const float4*)(apf + kb);
            float4 x1 = *(const float4*)(apf + kb + 4);
            ushort8v h, l;
            split8(x0, x1, h, l);
            *(ushort8v*)&sAh[arow * 32 + kchunk] = h;
            *(ushort8v*)&sAl[arow * 32 + kchunk] = l;
        } else {
            cp16(aph + kb, &sAh[w * 512]);
            cp16(apl + kb, &sAl[w * 512]);
        }
        __syncthreads();

        bf16x8 fah[4], fal[4], fbh[2], fbl[2];
        #pragma unroll
        for (int i = 0; i < 4; ++i) {
            fah[i] = *(const bf16x8*)&sAh[(i * 16 + mcol) * 32 + quad * 8];
            fal[i] = *(const bf16x8*)&sAl[(i * 16 + mcol) * 32 + quad * 8];
        }
        #pragma unroll
        for (int j = 0; j < 2; ++j) {
            fbh[j] = *(const bf16x8*)&sBh[(wc + j * 16 + mcol) * 32 + quad * 8];
            fbl[j] = *(const bf16x8*)&sBl[(wc + j * 16 + mcol) * 32 + quad * 8];
        }
        #pragma unroll
        for (int i = 0; i < 4; ++i)
            #pragma unroll
            for (int j = 0; j < 2; ++j) {
                acc[i][j] = __builtin_amdgcn_mfma_f32_16x16x32_bf16(fah[i], fbh[j], acc[i][j], 0, 0, 0);
                acc[i][j] = __builtin_amdgcn_mfma_f32_16x16x32_bf16(fah[i], fbl[j], acc[i][j], 0, 0, 0);
                acc[i][j] = __builtin_amdgcn_mfma_f32_16x16x32_bf16(fal[i], fbh[j], acc[i][j], 0, 0, 0);
            }
        __syncthreads();
    }

    float bb[2];
    #pragma unroll
    for (int j = 0; j < 2; ++j) bb[j] = bias ? bias[n0 + wc + j * 16 + mcol] : 0.f;

    #pragma unroll
    for (int i = 0; i < 4; ++i) {
        #pragma unroll
        for (int r = 0; r < 4; ++r) {
            int m = m0 + i * 16 + quad * 4 + r;
            if (m < M) {
                #pragma unroll
                for (int j = 0; j < 2; ++j) {
                    float v = acc[i][j][r] + bb[j];
                    size_t off = (size_t)m * ldc + n0 + wc + j * 16 + mcol;
                    if constexpr (BF16PAIR_OUT) {
                        unsigned short hh = f2bf_rne(v);
                        Ch[off] = hh;
                        Cl[off] = f2bf_rne(v - bf2f(hh));
                    } else {
                        Cf[off] = v;
                    }
                }
            }
        }
    }
}

// One WAVE per node. Two fp16 rows per load instruction:
// lanes 0-31 row 2p, lanes 32-63 row 2p+1, 16B/lane. Scores reduce over a
// 32-lane half (5 xor steps); lane l owns score 2*(l&31)+(l>>5).
// wstar is pre-folded into G, so score = G'.f_t directly.
template <int S>
__global__ __launch_bounds__(256) void attn_wave2(
    const int* __restrict__ node_ids, const int* __restrict__ neigh_ids,
    const float* __restrict__ G, const unsigned short* __restrict__ f16tab,
    float* __restrict__ mixf, int N)
{
    constexpr int SP1 = S + 1;          // 33
    constexpr int NP  = (SP1 + 1) / 2;  // 17 row-pairs
    const int w = threadIdx.x >> 6, l = threadIdx.x & 63;
    const int n = blockIdx.x * 4 + w;
    if (n >= N) return;

    const int h  = l >> 5;      // half: 0 = even rows, 1 = odd rows
    const int j  = l & 31;      // position within half

    int myid = 0;
    if (l < SP1) myid = (l == 0) ? node_ids[n] : neigh_ids[(size_t)n * S + (l - 1)];

    // G' chunk: dims j*8 .. j*8+7
    float4 g0 = ((const float4*)(G + (size_t)n * D))[j * 2];
    float4 g1 = ((const float4*)(G + (size_t)n * D))[j * 2 + 1];
    float gv[8] = {g0.x, g0.y, g0.z, g0.w, g1.x, g1.y, g1.z, g1.w};

    // load all row-pairs (16B/lane; 512B per row per 32 lanes)
    ushort8v rows[NP];
    #pragma unroll
    for (int p = 0; p < NP; ++p) {
        int rix = 2 * p + h; if (rix > SP1 - 1) rix = SP1 - 1;
        int idk = __shfl(myid, rix);
        rows[p] = ((const ushort8v*)(f16tab + (size_t)idk * D))[j];
    }

    // scores
    float score = -1e30f;
    #pragma unroll
    for (int p = 0; p < NP; ++p) {
        ushort8v r = rows[p];
        float s = 0.f;
        #pragma unroll
        for (int i = 0; i < 8; ++i) s = fmaf(gv[i], h2f(r[i]), s);
        #pragma unroll
        for (int off = 1; off < 32; off <<= 1) s += __shfl_xor(s, off);
        if (j == p) score = s;
    }
    const int myrow = 2 * j + h;
    if (myrow >= SP1) score = -1e30f;

    // softmax across all 64 lanes (permutation-invariant)
    float m = score;
    #pragma unroll
    for (int off = 1; off < 64; off <<= 1) m = fmaxf(m, __shfl_xor(m, off));
    float e = (myrow < SP1) ? __expf(score - m) : 0.f;
    float s = e;
    #pragma unroll
    for (int off = 1; off < 64; off <<= 1) s += __shfl_xor(s, off);
    float attn = e / s;

    // mix: half h accumulates its parity's rows, then combine halves
    float mix[8] = {0.f, 0.f, 0.f, 0.f, 0.f, 0.f, 0.f, 0.f};
    #pragma unroll
    for (int p = 0; p < NP; ++p) {
        float a = __shfl(attn, p + (l & 32));   // lane p (even) / 32+p (odd)
        ushort8v r = rows[p];
        #pragma unroll
        for (int i = 0; i < 8; ++i) mix[i] = fmaf(a, h2f(r[i]), mix[i]);
    }
    #pragma unroll
    for (int i = 0; i < 8; ++i) mix[i] += __shfl_xor(mix[i], 32);

    float4 v = {mix[4 * h + 0], mix[4 * h + 1], mix[4 * h + 2], mix[4 * h + 3]};
    ((float4*)(mixf + (size_t)n * D))[j * 2 + h] = v;
}

// generic fallback (S != 32)
__global__ __launch_bounds__(256) void attn_dyn(
    const int* __restrict__ node_ids, const int* __restrict__ neigh_ids,
    const float* __restrict__ G, const unsigned short* __restrict__ f16tab,
    float* __restrict__ mixf, int S)
{
    const int n = blockIdx.x, t = threadIdx.x;
    const int w = t >> 6, l = t & 63;
    __shared__ int   ids[128];
    __shared__ float sc[128];
    const int SP1 = S + 1;
    for (int k = t; k < SP1; k += 256)
        ids[k] = (k == 0) ? node_ids[n] : neigh_ids[(size_t)n * S + k - 1];
    __syncthreads();
    float4 g = ((const float4*)(G + (size_t)n * D))[l];
    for (int k = w; k < SP1; k += 4) {
        int id = ids[k];
        ushort4 h4 = ((const ushort4*)(f16tab + (size_t)id * D))[l];
        float p = g.x * h2f(h4.x) + g.y * h2f(h4.y) +
                  g.z * h2f(h4.z) + g.w * h2f(h4.w);
        #pragma unroll
        for (int off = 32; off > 0; off >>= 1) p += __shfl_down(p, off);
        if (l == 0) sc[k] = p;
    }
    __syncthreads();
    if (t < 64) {
        float v = (t < SP1) ? sc[t] : -1e30f;
        float m = v;
        #pragma unroll
        for (int off = 32; off > 0; off >>= 1) m = fmaxf(m, __shfl_down(m, off));
        m = __shfl(m, 0);
        float e = (t < SP1) ? __expf(v - m) : 0.f;
        float s = e;
        #pragma unroll
        for (int off = 32; off > 0; off >>= 1) s += __shfl_down(s, off);
        s = __shfl(s, 0);
        if (t < SP1) sc[t] = e / s;
    }
    __syncthreads();
    float mix = 0.f;
    for (int k = 0; k < SP1; ++k)
        mix = fmaf(sc[k], h2f(f16tab[(size_t)ids[k] * D + t]), mix);
    mixf[(size_t)n * D + t] = mix;
}

// out = tanh(P) / max(||tanh(P)||, 1e-12)  (one wave per row)
__global__ __launch_bounds__(256) void tanh_norm(
    const float* __restrict__ P, float* __restrict__ out, int N)
{
    const int w = threadIdx.x >> 6, l = threadIdx.x & 63;
    const int row = blockIdx.x * 4 + w;
    if (row >= N) return;
    float4 v = ((const float4*)(P + (size_t)row * D))[l];
    float4 o;
    o.x = tanhf(v.x); o.y = tanhf(v.y); o.z = tanhf(v.z); o.w = tanhf(v.w);
    float ss = o.x * o.x + o.y * o.y + o.z * o.z + o.w * o.w;
    #pragma unroll
    for (int off = 32; off > 0; off >>= 1) ss += __shfl_down(ss, off);
    ss = __shfl(ss, 0);
    float inv = 1.0f / fmaxf(sqrtf(ss), 1e-12f);
    o.x *= inv; o.y *= inv; o.z *= inv; o.w *= inv;
    ((float4*)(out + (size_t)row * D))[l] = o;
}

extern "C" void kernel_launch(void* const* d_in, const int* in_sizes, int n_in,
                              void* d_out, int out_size, void* d_ws, size_t ws_size,
                              hipStream_t stream) {
    const int*   node_ids  = (const int*)  d_in[0];
    const int*   neigh_ids = (const int*)  d_in[1];
    const float* feat      = (const float*)d_in[2];
    const float* Wq        = (const float*)d_in[3];
    const float* bq        = (const float*)d_in[4];
    const float* Wk        = (const float*)d_in[5];
    // bk (d_in[6]) is softmax-invariant — unused
    const float* Wv        = (const float*)d_in[7];
    const float* bv        = (const float*)d_in[8];
    float*       out       = (float*)d_out;

    const int N = in_sizes[0];            // 20000
    const int S = in_sizes[1] / N;        // 32
    const int T = in_sizes[2] / D;        // 100000

    // ---- workspace (~114 MB) ----
    unsigned short* f16tab = (unsigned short*)d_ws;             // T*D fp16
    float*          G      = (float*)(f16tab + (size_t)T * D);  // N*D f32
    float*          mixf   = G + (size_t)N * D;                 // N*D f32
    float*          P      = mixf + (size_t)N * D;              // N*D f32
    unsigned short* wqT_h  = (unsigned short*)(P + (size_t)N * D); // 6 x D*D
    unsigned short* wqT_l  = wqT_h + D * D;
    unsigned short* wkT_h  = wqT_l + D * D;
    unsigned short* wkT_l  = wkT_h + D * D;
    unsigned short* wv_h   = wkT_l + D * D;
    unsigned short* wv_l   = wv_h + D * D;
    unsigned short* MT_h   = wv_l + D * D;                      // 2 x D*D
    unsigned short* MT_l   = MT_h + D * D;
    float*          wstar  = (float*)(MT_l + D * D);            // D

    const int nbf = (T + 3) / 4;

    // 1) all conversions + wstar in ONE launch
    convert_all<<<nbf + 257, 256, 0, stream>>>(
        feat, T, nbf, Wq, Wk, Wv, bq, f16tab,
        wqT_h, wqT_l, wkT_h, wkT_l, wv_h, wv_l, wstar);

    // 2) MT = Wk^T Wq -> bf16 hi/lo pair
    {
        dim3 grid(4, 2);
        mfma_gemm64<true, false><<<grid, 256, 0, stream>>>(
            wkT_h, wkT_l, nullptr, nullptr, D, wqT_h, wqT_l, nullptr,
            nullptr, MT_h, MT_l, D);
    }
    // 3) G' = feat[node_ids] . MT + wstar   (wstar folded as bias)
    {
        dim3 grid((N + 63) / 64, 2);
        mfma_gemm64<false, true><<<grid, 256, 0, stream>>>(
            nullptr, nullptr, feat, node_ids, N, MT_h, MT_l, wstar,
            G, nullptr, nullptr, D);
    }
    // 4) attention -> mixfeat (f32)
    if (S == 32)
        attn_wave2<32><<<(N + 3) / 4, 256, 0, stream>>>(
            node_ids, neigh_ids, G, f16tab, mixf, N);
    else
        attn_dyn<<<N, 256, 0, stream>>>(node_ids, neigh_ids, G, f16tab, mixf, S);

    // 5) P = mixfeat @ Wv^T + bv
    {
        dim3 grid((N + 63) / 64, 2);
        mfma_gemm64<false, true><<<grid, 256, 0, stream>>>(
            nullptr, nullptr, mixf, nullptr, N, wv_h, wv_l, bv,
            P, nullptr, nullptr, D);
    }
    // 6) tanh + L2 normalize
    tanh_norm<<<(N + 3) / 4, 256, 0, stream>>>(P, out, N);
}

// Round 7
// 286.242 us; speedup vs baseline: 2.4674x; 1.0017x over previous
//
#include <hip/hip_runtime.h>
#include <hip/hip_bf16.h>

#define D 256

typedef __bf16 bf16x8 __attribute__((ext_vector_type(8)));
typedef float  f32x4  __attribute__((ext_vector_type(4)));
typedef unsigned short ushort8v __attribute__((ext_vector_type(8)));

static __device__ __forceinline__ unsigned short f2bf_rne(float f) {
    unsigned u = __float_as_uint(f);
    u += 0x7fff + ((u >> 16) & 1);
    return (unsigned short)(u >> 16);
}
static __device__ __forceinline__ float bf2f(unsigned short h) {
    return __uint_as_float(((unsigned)h) << 16);
}
static __device__ __forceinline__ unsigned short f2h(float f) {
    _Float16 h = (_Float16)f;
    unsigned short u; __builtin_memcpy(&u, &h, 2); return u;
}
static __device__ __forceinline__ float h2f(unsigned short u) {
    _Float16 h; __builtin_memcpy(&h, &u, 2); return (float)h;
}

static __device__ __forceinline__ void cp16(const unsigned short* g, unsigned short* l) {
    __builtin_amdgcn_global_load_lds(
        (const __attribute__((address_space(1))) void*)g,
        (__attribute__((address_space(3))) void*)l, 16, 0, 0);
}

static __device__ __forceinline__ void split8(float4 a, float4 b,
                                              ushort8v& h, ushort8v& l) {
    float v[8] = {a.x, a.y, a.z, a.w, b.x, b.y, b.z, b.w};
    #pragma unroll
    for (int i = 0; i < 8; ++i) {
        unsigned short hh = f2bf_rne(v[i]);
        h[i] = hh;
        l[i] = f2bf_rne(v[i] - bf2f(hh));
    }
}

// ONE launch: [0, nbf) feat->fp16 blocks; [nbf, nbf+256) weight-split blocks;
// block nbf+256 computes wstar = Wk^T bq.
__global__ __launch_bounds__(256) void convert_all(
    const float* __restrict__ feat, int T, int nbf,
    const float* __restrict__ Wq, const float* __restrict__ Wk,
    const float* __restrict__ Wv, const float* __restrict__ bq,
    unsigned short* __restrict__ f16tab,
    unsigned short* __restrict__ wqT_h, unsigned short* __restrict__ wqT_l,
    unsigned short* __restrict__ wkT_h, unsigned short* __restrict__ wkT_l,
    unsigned short* __restrict__ wv_h,  unsigned short* __restrict__ wv_l,
    float* __restrict__ wstar)
{
    const int bx = blockIdx.x;
    if (bx < nbf) {
        const int w = threadIdx.x >> 6, l = threadIdx.x & 63;
        const int row = bx * 4 + w;
        if (row >= T) return;
        float4 v = ((const float4*)(feat + (size_t)row * D))[l];
        ushort4 h;
        h.x = f2h(v.x); h.y = f2h(v.y); h.z = f2h(v.z); h.w = f2h(v.w);
        ((ushort4*)(f16tab + (size_t)row * D))[l] = h;
        return;
    }
    const int wb = bx - nbf;
    if (wb == 256) {
        int k = threadIdx.x;
        float s = 0.f;
        for (int n = 0; n < D; ++n) s = fmaf(Wk[n * D + k], bq[n], s);
        wstar[k] = s;
        return;
    }
    int i = wb * 256 + threadIdx.x;
    int r = i >> 8, cc = i & 255;
    int ti = cc * D + r;
    float q = Wq[i]; unsigned short qh = f2bf_rne(q);
    wqT_h[ti] = qh; wqT_l[ti] = f2bf_rne(q - bf2f(qh));
    float k = Wk[i]; unsigned short kh = f2bf_rne(k);
    wkT_h[ti] = kh; wkT_l[ti] = f2bf_rne(k - bf2f(kh));
    float v = Wv[i]; unsigned short vh = f2bf_rne(v);
    wv_h[i] = vh; wv_l[i] = f2bf_rne(v - bf2f(vh));
}

// C[m][n] = sum_k A[row(m)][k]*B[n][k] (+bias[n]).  BM=64 x BN tile, BK=32,
// 16x16x32 bf16 MFMA, 3-product hi/lo split (~f32 accuracy).
// AF32: A is f32 (optionally gathered via idx), split on the fly.
// FUSE: BN must equal ldc (=256, full rows in-block): epilogue applies
//       tanh + row L2-normalize and writes f32 directly.
template <int BN, bool PAIR_OUT, bool AF32, bool FUSE>
__global__ __launch_bounds__(256) void gemm_t(
    const unsigned short* __restrict__ Ah, const unsigned short* __restrict__ Al,
    const float* __restrict__ Af,
    const int* __restrict__ idx, int M,
    const unsigned short* __restrict__ Bh, const unsigned short* __restrict__ Bl,
    const float* __restrict__ bias,
    float* __restrict__ Cf, unsigned short* __restrict__ Ch,
    unsigned short* __restrict__ Cl, int ldc)
{
    constexpr int RW = BN / 4;        // cols (and staged B rows) per wave
    constexpr int JT = RW / 16;       // 16-wide col tiles per wave

    __shared__ __align__(16) unsigned short sAh[64 * 32], sAl[64 * 32];
    __shared__ __align__(16) unsigned short sBh[BN * 32], sBl[BN * 32];
    __shared__ float red[FUSE ? 256 : 4];

    const int t = threadIdx.x;
    const int w = t >> 6, lane = t & 63;
    const int quad = lane >> 4, mcol = lane & 15;
    const int m0 = blockIdx.x * 64, n0 = blockIdx.y * BN;

    const int arow = t >> 2;              // 0..63
    const int kchunk = (t & 3) * 8;

    int ar = m0 + arow; if (ar > M - 1) ar = M - 1;
    if (idx) ar = idx[ar];

    const unsigned short *aph = nullptr, *apl = nullptr;
    const float *apf = nullptr;
    if constexpr (AF32) {
        apf = Af + (size_t)ar * D + kchunk;
    } else {
        aph = Ah + (size_t)ar * D + kchunk;
        apl = Al + (size_t)ar * D + kchunk;
    }

    // B staging pointers: wave w stages rows [w*RW, w*RW+RW)
    const unsigned short* bh[JT];
    const unsigned short* bl[JT];
    #pragma unroll
    for (int p = 0; p < JT; ++p) {
        int row = n0 + w * RW + p * 16 + (lane >> 2);
        bh[p] = Bh + (size_t)row * D + kchunk;
        bl[p] = Bl + (size_t)row * D + kchunk;
    }

    f32x4 acc[4][JT];
    #pragma unroll
    for (int i = 0; i < 4; ++i)
        #pragma unroll
        for (int j = 0; j < JT; ++j) acc[i][j] = (f32x4){0.f, 0.f, 0.f, 0.f};

    #pragma unroll
    for (int kb = 0; kb < D; kb += 32) {
        #pragma unroll
        for (int p = 0; p < JT; ++p) {
            cp16(bh[p] + kb, &sBh[(w * RW + p * 16) * 32]);
            cp16(bl[p] + kb, &sBl[(w * RW + p * 16) * 32]);
        }
        if constexpr (AF32) {
            float4 x0 = *(const float4*)(apf + kb);
            float4 x1 = *(const float4*)(apf + kb + 4);
            ushort8v h, l;
            split8(x0, x1, h, l);
            *(ushort8v*)&sAh[arow * 32 + kchunk] = h;
            *(ushort8v*)&sAl[arow * 32 + kchunk] = l;
        } else {
            cp16(aph + kb, &sAh[w * 512]);
            cp16(apl + kb, &sAl[w * 512]);
        }
        __syncthreads();

        bf16x8 fah[4], fal[4], fbh[JT], fbl[JT];
        #pragma unroll
        for (int i = 0; i < 4; ++i) {
            fah[i] = *(const bf16x8*)&sAh[(i * 16 + mcol) * 32 + quad * 8];
            fal[i] = *(const bf16x8*)&sAl[(i * 16 + mcol) * 32 + quad * 8];
        }
        #pragma unroll
        for (int j = 0; j < JT; ++j) {
            fbh[j] = *(const bf16x8*)&sBh[(w * RW + j * 16 + mcol) * 32 + quad * 8];
            fbl[j] = *(const bf16x8*)&sBl[(w * RW + j * 16 + mcol) * 32 + quad * 8];
        }
        #pragma unroll
        for (int i = 0; i < 4; ++i)
            #pragma unroll
            for (int j = 0; j < JT; ++j) {
                acc[i][j] = __builtin_amdgcn_mfma_f32_16x16x32_bf16(fah[i], fbh[j], acc[i][j], 0, 0, 0);
                acc[i][j] = __builtin_amdgcn_mfma_f32_16x16x32_bf16(fah[i], fbl[j], acc[i][j], 0, 0, 0);
                acc[i][j] = __builtin_amdgcn_mfma_f32_16x16x32_bf16(fal[i], fbh[j], acc[i][j], 0, 0, 0);
            }
        __syncthreads();
    }

    float bb[JT];
    #pragma unroll
    for (int j = 0; j < JT; ++j) bb[j] = bias ? bias[n0 + w * RW + j * 16 + mcol] : 0.f;

    if constexpr (FUSE) {
        // tanh, then row-wise sum of squares
        float ss[4][4];
        #pragma unroll
        for (int i = 0; i < 4; ++i)
            #pragma unroll
            for (int r = 0; r < 4; ++r) {
                float s = 0.f;
                #pragma unroll
                for (int j = 0; j < JT; ++j) {
                    float v = tanhf(acc[i][j][r] + bb[j]);
                    acc[i][j][r] = v;
                    s = fmaf(v, v, s);
                }
                #pragma unroll
                for (int off = 1; off < 16; off <<= 1) s += __shfl_xor(s, off);
                ss[i][r] = s;
            }
        if (mcol == 0) {
            #pragma unroll
            for (int i = 0; i < 4; ++i)
                #pragma unroll
                for (int r = 0; r < 4; ++r)
                    red[(i * 16 + quad * 4 + r) * 4 + w] = ss[i][r];
        }
        __syncthreads();
        #pragma unroll
        for (int i = 0; i < 4; ++i)
            #pragma unroll
            for (int r = 0; r < 4; ++r) {
                int row = i * 16 + quad * 4 + r;
                float tot = red[row * 4] + red[row * 4 + 1] +
                            red[row * 4 + 2] + red[row * 4 + 3];
                float inv = 1.0f / fmaxf(sqrtf(tot), 1e-12f);
                int m = m0 + row;
                if (m < M) {
                    #pragma unroll
                    for (int j = 0; j < JT; ++j)
                        Cf[(size_t)m * ldc + n0 + w * RW + j * 16 + mcol] =
                            acc[i][j][r] * inv;
                }
            }
    } else {
        #pragma unroll
        for (int i = 0; i < 4; ++i) {
            #pragma unroll
            for (int r = 0; r < 4; ++r) {
                int m = m0 + i * 16 + quad * 4 + r;
                if (m < M) {
                    #pragma unroll
                    for (int j = 0; j < JT; ++j) {
                        float v = acc[i][j][r] + bb[j];
                        size_t off = (size_t)m * ldc + n0 + w * RW + j * 16 + mcol;
                        if constexpr (PAIR_OUT) {
                            unsigned short hh = f2bf_rne(v);
                            Ch[off] = hh;
                            Cl[off] = f2bf_rne(v - bf2f(hh));
                        } else {
                            Cf[off] = v;
                        }
                    }
                }
            }
        }
    }
}

// One WAVE per node. Two fp16 rows per load instruction:
// lanes 0-31 row 2p, lanes 32-63 row 2p+1, 16B/lane. Scores reduce over a
// 32-lane half (5 xor steps); lane l owns score 2*(l&31)+(l>>5).
// wstar is pre-folded into G, so score = G'.f_t directly.
template <int S>
__global__ __launch_bounds__(256) void attn_wave2(
    const int* __restrict__ node_ids, const int* __restrict__ neigh_ids,
    const float* __restrict__ G, const unsigned short* __restrict__ f16tab,
    float* __restrict__ mixf, int N)
{
    constexpr int SP1 = S + 1;          // 33
    constexpr int NP  = (SP1 + 1) / 2;  // 17 row-pairs
    const int w = threadIdx.x >> 6, l = threadIdx.x & 63;
    const int n = blockIdx.x * 4 + w;
    if (n >= N) return;

    const int h  = l >> 5;      // half: 0 = even rows, 1 = odd rows
    const int j  = l & 31;      // position within half

    int myid = 0;
    if (l < SP1) myid = (l == 0) ? node_ids[n] : neigh_ids[(size_t)n * S + (l - 1)];

    // G' chunk: dims j*8 .. j*8+7
    float4 g0 = ((const float4*)(G + (size_t)n * D))[j * 2];
    float4 g1 = ((const float4*)(G + (size_t)n * D))[j * 2 + 1];
    float gv[8] = {g0.x, g0.y, g0.z, g0.w, g1.x, g1.y, g1.z, g1.w};

    // load all row-pairs (16B/lane; 512B per row per 32 lanes)
    ushort8v rows[NP];
    #pragma unroll
    for (int p = 0; p < NP; ++p) {
        int rix = 2 * p + h; if (rix > SP1 - 1) rix = SP1 - 1;
        int idk = __shfl(myid, rix);
        rows[p] = ((const ushort8v*)(f16tab + (size_t)idk * D))[j];
    }

    // scores
    float score = -1e30f;
    #pragma unroll
    for (int p = 0; p < NP; ++p) {
        ushort8v r = rows[p];
        float s = 0.f;
        #pragma unroll
        for (int i = 0; i < 8; ++i) s = fmaf(gv[i], h2f(r[i]), s);
        #pragma unroll
        for (int off = 1; off < 32; off <<= 1) s += __shfl_xor(s, off);
        if (j == p) score = s;
    }
    const int myrow = 2 * j + h;
    if (myrow >= SP1) score = -1e30f;

    // softmax across all 64 lanes (permutation-invariant)
    float m = score;
    #pragma unroll
    for (int off = 1; off < 64; off <<= 1) m = fmaxf(m, __shfl_xor(m, off));
    float e = (myrow < SP1) ? __expf(score - m) : 0.f;
    float s = e;
    #pragma unroll
    for (int off = 1; off < 64; off <<= 1) s += __shfl_xor(s, off);
    float attn = e / s;

    // mix: half h accumulates its parity's rows, then combine halves
    float mix[8] = {0.f, 0.f, 0.f, 0.f, 0.f, 0.f, 0.f, 0.f};
    #pragma unroll
    for (int p = 0; p < NP; ++p) {
        float a = __shfl(attn, p + (l & 32));   // lane p (even) / 32+p (odd)
        ushort8v r = rows[p];
        #pragma unroll
        for (int i = 0; i < 8; ++i) mix[i] = fmaf(a, h2f(r[i]), mix[i]);
    }
    #pragma unroll
    for (int i = 0; i < 8; ++i) mix[i] += __shfl_xor(mix[i], 32);

    float4 v = {mix[4 * h + 0], mix[4 * h + 1], mix[4 * h + 2], mix[4 * h + 3]};
    ((float4*)(mixf + (size_t)n * D))[j * 2 + h] = v;
}

// generic fallback (S != 32)
__global__ __launch_bounds__(256) void attn_dyn(
    const int* __restrict__ node_ids, const int* __restrict__ neigh_ids,
    const float* __restrict__ G, const unsigned short* __restrict__ f16tab,
    float* __restrict__ mixf, int S)
{
    const int n = blockIdx.x, t = threadIdx.x;
    const int w = t >> 6, l = t & 63;
    __shared__ int   ids[128];
    __shared__ float sc[128];
    const int SP1 = S + 1;
    for (int k = t; k < SP1; k += 256)
        ids[k] = (k == 0) ? node_ids[n] : neigh_ids[(size_t)n * S + k - 1];
    __syncthreads();
    float4 g = ((const float4*)(G + (size_t)n * D))[l];
    for (int k = w; k < SP1; k += 4) {
        int id = ids[k];
        ushort4 h4 = ((const ushort4*)(f16tab + (size_t)id * D))[l];
        float p = g.x * h2f(h4.x) + g.y * h2f(h4.y) +
                  g.z * h2f(h4.z) + g.w * h2f(h4.w);
        #pragma unroll
        for (int off = 32; off > 0; off >>= 1) p += __shfl_down(p, off);
        if (l == 0) sc[k] = p;
    }
    __syncthreads();
    if (t < 64) {
        float v = (t < SP1) ? sc[t] : -1e30f;
        float m = v;
        #pragma unroll
        for (int off = 32; off > 0; off >>= 1) m = fmaxf(m, __shfl_down(m, off));
        m = __shfl(m, 0);
        float e = (t < SP1) ? __expf(v - m) : 0.f;
        float s = e;
        #pragma unroll
        for (int off = 32; off > 0; off >>= 1) s += __shfl_down(s, off);
        s = __shfl(s, 0);
        if (t < SP1) sc[t] = e / s;
    }
    __syncthreads();
    float mix = 0.f;
    for (int k = 0; k < SP1; ++k)
        mix = fmaf(sc[k], h2f(f16tab[(size_t)ids[k] * D + t]), mix);
    mixf[(size_t)n * D + t] = mix;
}

extern "C" void kernel_launch(void* const* d_in, const int* in_sizes, int n_in,
                              void* d_out, int out_size, void* d_ws, size_t ws_size,
                              hipStream_t stream) {
    const int*   node_ids  = (const int*)  d_in[0];
    const int*   neigh_ids = (const int*)  d_in[1];
    const float* feat      = (const float*)d_in[2];
    const float* Wq        = (const float*)d_in[3];
    const float* bq        = (const float*)d_in[4];
    const float* Wk        = (const float*)d_in[5];
    // bk (d_in[6]) is softmax-invariant — unused
    const float* Wv        = (const float*)d_in[7];
    const float* bv        = (const float*)d_in[8];
    float*       out       = (float*)d_out;

    const int N = in_sizes[0];            // 20000
    const int S = in_sizes[1] / N;        // 32
    const int T = in_sizes[2] / D;        // 100000

    // ---- workspace (~94 MB) ----
    unsigned short* f16tab = (unsigned short*)d_ws;             // T*D fp16
    float*          G      = (float*)(f16tab + (size_t)T * D);  // N*D f32
    float*          mixf   = G + (size_t)N * D;                 // N*D f32
    unsigned short* wqT_h  = (unsigned short*)(mixf + (size_t)N * D); // 6 x D*D
    unsigned short* wqT_l  = wqT_h + D * D;
    unsigned short* wkT_h  = wqT_l + D * D;
    unsigned short* wkT_l  = wkT_h + D * D;
    unsigned short* wv_h   = wkT_l + D * D;
    unsigned short* wv_l   = wv_h + D * D;
    unsigned short* MT_h   = wv_l + D * D;                      // 2 x D*D
    unsigned short* MT_l   = MT_h + D * D;
    float*          wstar  = (float*)(MT_l + D * D);            // D

    const int nbf = (T + 3) / 4;

    // 1) all conversions + wstar in ONE launch
    convert_all<<<nbf + 257, 256, 0, stream>>>(
        feat, T, nbf, Wq, Wk, Wv, bq, f16tab,
        wqT_h, wqT_l, wkT_h, wkT_l, wv_h, wv_l, wstar);

    // 2) MT = Wk^T Wq -> bf16 hi/lo pair
    {
        dim3 grid(4, 2);
        gemm_t<128, true, false, false><<<grid, 256, 0, stream>>>(
            wkT_h, wkT_l, nullptr, nullptr, D, wqT_h, wqT_l, nullptr,
            nullptr, MT_h, MT_l, D);
    }
    // 3) G' = feat[node_ids] . MT + wstar   (wstar folded as bias)
    {
        dim3 grid((N + 63) / 64, 2);
        gemm_t<128, false, true, false><<<grid, 256, 0, stream>>>(
            nullptr, nullptr, feat, node_ids, N, MT_h, MT_l, wstar,
            G, nullptr, nullptr, D);
    }
    // 4) attention -> mixfeat (f32)
    if (S == 32)
        attn_wave2<32><<<(N + 3) / 4, 256, 0, stream>>>(
            node_ids, neigh_ids, G, f16tab, mixf, N);
    else
        attn_dyn<<<N, 256, 0, stream>>>(node_ids, neigh_ids, G, f16tab, mixf, S);

    // 5) out = normalize(tanh(mixfeat @ Wv^T + bv))  — fused epilogue
    {
        dim3 grid((N + 63) / 64, 1);
        gemm_t<256, false, true, true><<<grid, 256, 0, stream>>>(
            nullptr, nullptr, mixf, nullptr, N, wv_h, wv_l, bv,
            out, nullptr, nullptr, D);
    }
}